// Round 10
// baseline (638.923 us; speedup 1.0000x reference)
//
#include <hip/hip_runtime.h>
#include <stdint.h>

typedef unsigned short u16;
typedef u16 u16x8 __attribute__((ext_vector_type(8)));
typedef __bf16 bf16x8 __attribute__((ext_vector_type(8)));
typedef float f32x4 __attribute__((ext_vector_type(4)));
typedef float f32x16 __attribute__((ext_vector_type(16)));

#define NE   256
#define NPOS 40960     // 32*64*4*5
#define QLD  768       // QKV row stride (seq only now)

__device__ __forceinline__ float bf2f(u16 h) {
  union { unsigned u; float f; } c; c.u = ((unsigned)h) << 16; return c.f;
}
__device__ __forceinline__ u16 f2bf(float f) {
  union { float f; unsigned u; } c; c.f = f;
  unsigned u = c.u;
  return (u16)((u + 0x7FFFu + ((u >> 16) & 1u)) >> 16);
}
__device__ __forceinline__ unsigned pkbf(float a, float b) {
  unsigned r;
  asm("v_cvt_pk_bf16_f32 %0, %1, %2" : "=v"(r) : "v"(a), "v"(b));
  return r;
}
__device__ __forceinline__ void gll16(const void* g, void* l) {
  __builtin_amdgcn_global_load_lds(
      (const __attribute__((address_space(1))) void*)g,
      (__attribute__((address_space(3))) void*)l, 16, 0, 0);
}
template<int N> __device__ __forceinline__ void waitvm() {
  if constexpr (N == 0)       asm volatile("s_waitcnt vmcnt(0)"  ::: "memory");
  else if constexpr (N == 4)  asm volatile("s_waitcnt vmcnt(4)"  ::: "memory");
  else if constexpr (N == 6)  asm volatile("s_waitcnt vmcnt(6)"  ::: "memory");
  else if constexpr (N == 8)  asm volatile("s_waitcnt vmcnt(8)"  ::: "memory");
  else if constexpr (N == 12) asm volatile("s_waitcnt vmcnt(12)" ::: "memory");
}

// ---------------------------------------------------------------------------
// prep: xb[n][e] = bf16(x[b,s,e,h,w] + pos), n = ((b*64+s)*4+h)*5+w
// ---------------------------------------------------------------------------
__global__ __launch_bounds__(256) void prep_kernel(
    const float* __restrict__ x, const float* __restrict__ pos_s,
    const float* __restrict__ pos_h, const float* __restrict__ pos_w,
    u16* __restrict__ xb)
{
  __shared__ float Ls[256 * 21];
  const int bs = blockIdx.x;           // b*64+s
  const int s  = bs & 63;
  const int tid = threadIdx.x;
  const float* xp = x + (size_t)bs * 5120;
  for (int i = tid; i < 5120; i += 256) {
    int e = i / 20, hw = i % 20;
    int h = hw / 5, w = hw % 5;
    float v = xp[i] + pos_s[s * 256 + e] + pos_h[e * 4 + h] + pos_w[e * 5 + w];
    Ls[e * 21 + hw] = v;
  }
  __syncthreads();
  u16* op = xb + (size_t)bs * 20 * 256;
  for (int i = tid; i < 5120; i += 256) {
    int nl = i >> 8, e = i & 255;
    op[nl * 256 + e] = f2bf(Ls[e * 21 + nl]);
  }
}

// ---------------------------------------------------------------------------
// all weight packing in one dispatch
// ---------------------------------------------------------------------------
#define PK_T1 (6*768*256)
#define PK_T2 (2*256*768)
__global__ __launch_bounds__(256) void pack_all(
    const float* __restrict__ wq, const float* __restrict__ wkv,
    const float* __restrict__ wo, const float* __restrict__ wo_b,
    u16* __restrict__ wqp, u16* __restrict__ wop, float* __restrict__ bsum)
{
  int i = blockIdx.x * 256 + threadIdx.x;
  if (i < PK_T1) {
    int la = i / (768 * 256);
    int rem = i - la * (768 * 256);
    int r = rem >> 8, c = rem & 255;
    float v = (r < 256) ? wq[(size_t)la * 65536 + r * 256 + c] * 0.25f
                        : wkv[(size_t)la * 131072 + (r - 256) * 256 + c];
    wqp[i] = f2bf(v);
  } else if (i < PK_T1 + PK_T2) {
    int j = i - PK_T1;
    int l = j / 196608;
    int rem = j - l * 196608;
    int out = rem / 768, k = rem % 768;
    int a = k >> 8, in = k & 255;
    wop[j] = f2bf(wo[(size_t)(((l * 3 + a) * 256) + out) * 256 + in]);
  } else if (i < PK_T1 + PK_T2 + 512) {
    int j = i - PK_T1 - PK_T2;
    int l = j >> 8, c = j & 255;
    bsum[j] = wo_b[(l * 3 + 0) * 256 + c] + wo_b[(l * 3 + 1) * 256 + c]
            + wo_b[(l * 3 + 2) * 256 + c];
  }
}

// ---------------------------------------------------------------------------
// GEMM: C[M][N] = A[M][K] * B[N][K]^T   (A,B bf16; acc f32)
// 128x128 tile, triple-buffered LDS, 2-deep counted-vmcnt prefetch,
// XCD-chunked bijective swizzle (bn-fastest within chunk).
// MODE 0: store bf16 at ldc; 3: Cb = bf16(acc+bias); 4: fused decode partial
// ---------------------------------------------------------------------------
template<int MODE, int NKT, int NBN>
__global__ __launch_bounds__(256, 2) void gemm_bt(
    const u16* __restrict__ A, const u16* __restrict__ B,
    u16* __restrict__ Cb, const float* __restrict__ bias,
    const float* __restrict__ dw, float* __restrict__ logit,
    int ldc)
{
  constexpr int K   = NKT * 32;
  constexpr int BN  = 128;
  constexpr int NF  = BN / 32;
  constexpr int LPT = 2 + BN / 64;
  constexpr int ASZ = 128 * 32;
  constexpr int TSZ = (128 + BN) * 32;
  static_assert(NKT >= 2, "");

  __shared__ alignas(16) u16 smem[3 * TSZ];

  const int bid = blockIdx.x;
  const int cpx = gridDim.x >> 3;
  const int mapped = (bid & 7) * cpx + (bid >> 3);
  const int bm = mapped / NBN, bn = mapped % NBN;

  const int tid  = threadIdx.x;
  const int lane = tid & 63, w = tid >> 6;
  const int wr   = (w >> 1) * 64, wc = (w & 1) * (BN / 2);
  const int r16  = lane & 15, khi = lane >> 4;

  f32x4 acc[4][NF] = {};

  const u16* gA = A + (size_t)bm * 128 * K;
  const u16* gB = B + (size_t)bn * BN * K;

  auto STAGE = [&](int kt, int which) {
    u16* As = smem + which * TSZ;
    u16* Bs = As + ASZ;
    const u16* tA = gA + kt * 32;
    const u16* tB = gB + kt * 32;
    #pragma unroll
    for (int r = 0; r < 2; ++r) {
      int i = tid + r * 256;
      int row = i >> 2, seg = (i & 3) << 3;
      gll16(tA + (size_t)row * K + seg, (char*)As + i * 16);
    }
    #pragma unroll
    for (int r = 0; r < BN / 64; ++r) {
      int i = tid + r * 256;
      int row = i >> 2, seg = (i & 3) << 3;
      gll16(tB + (size_t)row * K + seg, (char*)Bs + i * 16);
    }
  };

  STAGE(0, 0);
  STAGE(1, 1);
  #pragma unroll
  for (int kt = 0; kt < NKT; ++kt) {
    const int cur = kt % 3;
    if (kt + 2 < NKT)      { STAGE(kt + 2, (kt + 2) % 3); waitvm<2 * LPT>(); }
    else if (kt + 1 < NKT) { waitvm<LPT>(); }
    else                   { waitvm<0>(); }
    __builtin_amdgcn_s_barrier();
    asm volatile("" ::: "memory");

    const u16* As = smem + cur * TSZ;
    const u16* Bs = As + ASZ;
    bf16x8 af[4], bfr[NF];
    #pragma unroll
    for (int m = 0; m < 4; ++m)
      af[m] = *(const bf16x8*)(As + (wr + m * 16 + r16) * 32 + khi * 8);
    #pragma unroll
    for (int n = 0; n < NF; ++n)
      bfr[n] = *(const bf16x8*)(Bs + (wc + n * 16 + r16) * 32 + khi * 8);
    #pragma unroll
    for (int m = 0; m < 4; ++m)
      #pragma unroll
      for (int n = 0; n < NF; ++n)
        acc[m][n] = __builtin_amdgcn_mfma_f32_16x16x32_bf16(af[m], bfr[n], acc[m][n], 0, 0, 0);

    asm volatile("" ::: "memory");
    __builtin_amdgcn_s_barrier();
  }

  const int row0 = bm * 128 + wr + khi * 4;
  const int col0 = bn * BN + wc + r16;

  if constexpr (MODE == 4) {
    float dwv[NF], bvv[NF];
    #pragma unroll
    for (int n = 0; n < NF; ++n) {
      int c = col0 + n * 16;
      dwv[n] = dw[c];
      bvv[n] = bias[c];
    }
    #pragma unroll
    for (int m = 0; m < 4; ++m) {
      #pragma unroll
      for (int j = 0; j < 4; ++j) {
        float p = 0.f;
        #pragma unroll
        for (int n = 0; n < NF; ++n) p += (acc[m][n][j] + bvv[n]) * dwv[n];
        p += __shfl_xor(p, 1);
        p += __shfl_xor(p, 2);
        p += __shfl_xor(p, 4);
        p += __shfl_xor(p, 8);
        if (r16 == 0) atomicAdd(&logit[row0 + m * 16 + j], p);
      }
    }
  } else {
    #pragma unroll
    for (int m = 0; m < 4; ++m) {
      #pragma unroll
      for (int n = 0; n < NF; ++n) {
        int c = col0 + n * 16;
        float bv = (MODE == 3) ? bias[c] : 0.f;
        #pragma unroll
        for (int j = 0; j < 4; ++j) {
          int r = row0 + m * 16 + j;
          Cb[(size_t)r * ldc + c] = f2bf(acc[m][n][j] + bv);
        }
      }
    }
  }
}

// ---------------------------------------------------------------------------
// seq-axis attention via MFMA. One wave = one (group g, head hd).
// QKV [NPOS][768] bf16 (q|k|v). Writes Ob cols 0..255 (ld 768).
// ---------------------------------------------------------------------------
__global__ __launch_bounds__(256) void attn_seq_mfma(
    const u16* __restrict__ QKV, u16* __restrict__ Ob)
{
  const int w = threadIdx.x >> 6, lane = threadIdx.x & 63;
  const int wid = blockIdx.x * 4 + w;
  const int hd = wid & 15, g = wid >> 4;          // g in [0,640)
  const int gb = g / 20, gr = g % 20;
  const int nbase = gb * 1280 + gr;               // + pos*20
  const int lo = lane & 31, hi = lane >> 5;

  bf16x8 kf[2], qf[2];
  #pragma unroll
  for (int t = 0; t < 2; ++t) {
    size_t r = (size_t)(nbase + (lo + 32 * t) * 20) * QLD;
    kf[t] = *(const bf16x8*)(QKV + r + 256 + hd * 16 + hi * 8);
    qf[t] = *(const bf16x8*)(QKV + r +       hd * 16 + hi * 8);
  }
  union { u16 a[8]; bf16x8 v; } vt[4];
  #pragma unroll
  for (int c = 0; c < 4; ++c)
    #pragma unroll
    for (int j = 0; j < 8; ++j)
      vt[c].a[j] = QKV[(size_t)(nbase + (c * 16 + hi * 8 + j) * 20) * QLD
                       + 512 + hd * 16 + lo];

  f32x16 s00 = {}, s10 = {}, s01 = {}, s11 = {};   // s[kt][qt]
  s00 = __builtin_amdgcn_mfma_f32_32x32x16_bf16(kf[0], qf[0], s00, 0, 0, 0);
  s10 = __builtin_amdgcn_mfma_f32_32x32x16_bf16(kf[1], qf[0], s10, 0, 0, 0);
  s01 = __builtin_amdgcn_mfma_f32_32x32x16_bf16(kf[0], qf[1], s01, 0, 0, 0);
  s11 = __builtin_amdgcn_mfma_f32_32x32x16_bf16(kf[1], qf[1], s11, 0, 0, 0);

  auto run_qt = [&](f32x16 t0, f32x16 t1, int qt) {
    float m = -1e30f;
    #pragma unroll
    for (int r = 0; r < 16; ++r) { m = fmaxf(m, t0[r]); m = fmaxf(m, t1[r]); }
    m = fmaxf(m, __shfl_xor(m, 32));
    const float C = 1.4426950408889634f;           // log2(e); 0.25 folded in wq
    float mc = m * C;
    float sum = 0.f;
    #pragma unroll
    for (int r = 0; r < 16; ++r) {
      float p0 = __builtin_amdgcn_exp2f(t0[r] * C - mc);
      float p1 = __builtin_amdgcn_exp2f(t1[r] * C - mc);
      t0[r] = p0; t1[r] = p1; sum += p0; sum += p1;
    }
    sum += __shfl_xor(sum, 32);
    float inv = __builtin_amdgcn_rcpf(sum);
    #pragma unroll
    for (int r = 0; r < 16; ++r) { t0[r] *= inv; t1[r] *= inv; }

    f32x16 oa = {};
    #pragma unroll
    for (int c = 0; c < 4; ++c) {
      const int rb = 8 * (c & 1);
      const f32x16& tt = (c < 2) ? t0 : t1;
      unsigned X0 = pkbf(tt[rb + 0], tt[rb + 1]);
      unsigned X1 = pkbf(tt[rb + 2], tt[rb + 3]);
      unsigned Y0 = pkbf(tt[rb + 4], tt[rb + 5]);
      unsigned Y1 = pkbf(tt[rb + 6], tt[rb + 7]);
      unsigned X0p = __shfl_xor((int)X0, 32), X1p = __shfl_xor((int)X1, 32);
      unsigned Y0p = __shfl_xor((int)Y0, 32), Y1p = __shfl_xor((int)Y1, 32);
      union { unsigned u[4]; bf16x8 v; } pf;
      pf.u[0] = hi ? Y0p : X0;
      pf.u[1] = hi ? Y1p : X1;
      pf.u[2] = hi ? Y0  : X0p;
      pf.u[3] = hi ? Y1  : X1p;
      oa = __builtin_amdgcn_mfma_f32_32x32x16_bf16(vt[c].v, pf.v, oa, 0, 0, 0);
    }
    unsigned P0 = pkbf(oa[0], oa[1]);
    unsigned P1 = pkbf(oa[2], oa[3]);
    unsigned P2 = pkbf(oa[4], oa[5]);
    unsigned P3 = pkbf(oa[6], oa[7]);
    unsigned sP0 = __shfl_xor((int)P0, 32), sP1 = __shfl_xor((int)P1, 32);
    unsigned sP2 = __shfl_xor((int)P2, 32), sP3 = __shfl_xor((int)P3, 32);
    union { unsigned u[4]; u16x8 v; } ov;
    ov.u[0] = hi ? sP2 : P0;
    ov.u[1] = hi ? sP3 : P1;
    ov.u[2] = hi ? P2  : sP0;
    ov.u[3] = hi ? P3  : sP1;
    u16* po = Ob + (size_t)(nbase + (qt * 32 + lo) * 20) * 768 + hd * 16 + hi * 8;
    *(u16x8*)po = ov.v;
  };
  run_qt(s00, s10, 0);
  run_qt(s01, s11, 1);
}

// ---------------------------------------------------------------------------
// fused H+W projection + attention. Block = 80 rows (4 (b,s)-planes),
// 320 threads = 5 waves (wave = 16 rows). Per axis:
//   MFMA phase: per head, 3 n-frags (q|k|v) x 8 k-steps, A-frags hoisted in
//     regs, B-frags straight from L2-hot weights; result -> bf16 LDS [80][776]
//   barrier; attention phase: thread = (group, head), T=4 (H) / 5 (W)
// Writes Ob cols 256..511 (H) and 512..767 (W). No QKV materialization.
// ---------------------------------------------------------------------------
__global__ __launch_bounds__(320) void fused_hw(
    const u16* __restrict__ xb, const u16* __restrict__ wqp_l,
    u16* __restrict__ Ob)
{
  __shared__ u16 qkv[80][776];
  const int tid = threadIdx.x;
  const int w = tid >> 6, lane = tid & 63;
  const int n0 = blockIdx.x * 80;
  const int r16 = lane & 15, khi = lane >> 4;
  const int arow = n0 + w * 16 + r16;

  // A-frags: wave's 16 rows x K=256, reused across heads and axes
  bf16x8 af[8];
  #pragma unroll
  for (int ks = 0; ks < 8; ++ks)
    af[ks] = *(const bf16x8*)(xb + (size_t)arow * 256 + ks * 32 + khi * 8);

  #pragma unroll
  for (int axis = 0; axis < 2; ++axis) {
    const u16* wb = wqp_l + (size_t)axis * 196608;
    if (axis) __syncthreads();         // axis-0 attention reads done

    // ---- MFMA phase: all 16 heads -> LDS ----
    for (int hd = 0; hd < 16; ++hd) {
      f32x4 acc[3] = {};
      #pragma unroll
      for (int nf = 0; nf < 3; ++nf) {
        const u16* wrow = wb + (size_t)(nf * 256 + hd * 16 + r16) * 256;
        #pragma unroll
        for (int ks = 0; ks < 8; ++ks) {
          bf16x8 bf = *(const bf16x8*)(wrow + ks * 32 + khi * 8);
          acc[nf] = __builtin_amdgcn_mfma_f32_16x16x32_bf16(af[ks], bf, acc[nf], 0, 0, 0);
        }
      }
      #pragma unroll
      for (int nf = 0; nf < 3; ++nf)
        #pragma unroll
        for (int j = 0; j < 4; ++j)
          qkv[w * 16 + khi * 4 + j][nf * 256 + hd * 16 + r16] = f2bf(acc[nf][j]);
    }
    __syncthreads();

    // ---- attention phase ----
    const int T = axis ? 5 : 4;
    const int ng = axis ? 16 : 20;
    if (tid < ng * 16) {
      const int g = tid >> 4, hd = tid & 15;
      int rbase, rstp;
      if (axis == 0) { rbase = (g / 5) * 20 + (g % 5);     rstp = 5; }
      else           { rbase = (g / 4) * 20 + (g % 4) * 5; rstp = 1; }
      // preload k
      float kk[5][16];
      #pragma unroll
      for (int j = 0; j < 5; ++j) {
        if (j < T) {
          const u16* kp = &qkv[rbase + j * rstp][256 + hd * 16];
          u16x8 a0 = *(const u16x8*)kp, a1 = *(const u16x8*)(kp + 8);
          #pragma unroll
          for (int d = 0; d < 8; ++d) {
            kk[j][d] = bf2f(a0[d]); kk[j][d + 8] = bf2f(a1[d]);
          }
        }
      }
      for (int i = 0; i < T; ++i) {
        const int r = rbase + i * rstp;
        const u16* qp = &qkv[r][hd * 16];
        u16x8 q0 = *(const u16x8*)qp, q1 = *(const u16x8*)(qp + 8);
        float q[16];
        #pragma unroll
        for (int d = 0; d < 8; ++d) { q[d] = bf2f(q0[d]); q[d + 8] = bf2f(q1[d]); }
        float s[5], m = -1e30f;
        #pragma unroll
        for (int j = 0; j < 5; ++j) {
          if (j < T) {
            float a = 0.f;
            #pragma unroll
            for (int d = 0; d < 16; ++d) a += q[d] * kk[j][d];
            s[j] = a; m = fmaxf(m, a);
          }
        }
        float sum = 0.f, o[16];
        #pragma unroll
        for (int d = 0; d < 16; ++d) o[d] = 0.f;
        #pragma unroll
        for (int j = 0; j < 5; ++j) {
          if (j < T) {
            float pj = __expf(s[j] - m);
            sum += pj;
            const u16* vp = &qkv[rbase + j * rstp][512 + hd * 16];
            u16x8 v0 = *(const u16x8*)vp, v1 = *(const u16x8*)(vp + 8);
            #pragma unroll
            for (int d = 0; d < 8; ++d) {
              o[d] += pj * bf2f(v0[d]); o[d + 8] += pj * bf2f(v1[d]);
            }
          }
        }
        float inv = 1.0f / sum;
        u16x8 r0, r1;
        #pragma unroll
        for (int d = 0; d < 8; ++d) {
          r0[d] = f2bf(o[d] * inv); r1[d] = f2bf(o[d + 8] * inv);
        }
        u16* po = Ob + (size_t)(n0 + r) * 768 + 256 + axis * 256 + hd * 16;
        *(u16x8*)(po)     = r0;
        *(u16x8*)(po + 8) = r1;
      }
    }
  }
}

// ---------------------------------------------------------------------------
// final sigmoid over accumulated logits
// ---------------------------------------------------------------------------
__global__ __launch_bounds__(256) void sigmoid_kernel(
    const float* __restrict__ logit, const float* __restrict__ dec_b,
    float* __restrict__ out)
{
  int i = blockIdx.x * 256 + threadIdx.x;
  out[i] = 1.0f / (1.0f + __expf(-(logit[i] + dec_b[0])));
}

// ---------------------------------------------------------------------------
extern "C" void kernel_launch(void* const* d_in, const int* in_sizes, int n_in,
                              void* d_out, int out_size, void* d_ws, size_t ws_size,
                              hipStream_t stream) {
  const float* x     = (const float*)d_in[0];
  const float* pos_s = (const float*)d_in[1];
  const float* pos_h = (const float*)d_in[2];
  const float* pos_w = (const float*)d_in[3];
  const float* wq    = (const float*)d_in[4];   // (2,3,256,256)
  const float* wkv   = (const float*)d_in[5];   // (2,3,512,256)
  const float* wo_w  = (const float*)d_in[6];   // (2,3,256,256)
  const float* wo_b  = (const float*)d_in[7];   // (2,3,256)
  const float* dec_w = (const float*)d_in[8];   // (1,256)
  const float* dec_b = (const float*)d_in[9];   // (1,)
  float* out = (float*)d_out;

  char* ws = (char*)d_ws;
  u16*   xb    = (u16*)ws;                       // 20,971,520
  u16*   Ob    = (u16*)(ws + 20971520);          // 62,914,560
  u16*   QKV   = (u16*)(ws + 83886080);          // 40960*768*2 = 62,914,560
  u16*   wqp   = (u16*)(ws + 146800640);         // 2,359,296
  u16*   wop   = (u16*)(ws + 149159936);         // 786,432
  float* bsum  = (float*)(ws + 149946368);       // 2,048
  float* logit = (float*)(ws + 149948416);       // 163,840  (end ~150 MB)

  prep_kernel<<<2048, 256, 0, stream>>>(x, pos_s, pos_h, pos_w, xb);
  pack_all<<<(PK_T1 + PK_T2 + 512 + 255) / 256, 256, 0, stream>>>(
      wq, wkv, wo_w, wo_b, wqp, wop, bsum);
  hipMemsetAsync(logit, 0, NPOS * sizeof(float), stream);

  for (int l = 0; l < 2; ++l) {
    // seq axis: QKV (768 cols), then MFMA attention -> Ob cols 0..255
    gemm_bt<0, 8, 6><<<320 * 6, 256, 0, stream>>>(
        xb, wqp + (size_t)(l * 3) * 196608, QKV, nullptr, nullptr, nullptr, QLD);
    attn_seq_mfma<<<2560, 256, 0, stream>>>(QKV, Ob);
    // H+W axes fused: projection + attention -> Ob cols 256..767
    fused_hw<<<NPOS / 80, 320, 0, stream>>>(
        xb, wqp + (size_t)(l * 3 + 1) * 196608, Ob);
    // merged out-projection (K=768)
    if (l == 0)
      gemm_bt<3, 24, 2><<<320 * 2, 256, 0, stream>>>(
          Ob, wop, xb, bsum, nullptr, nullptr, 256);
    else
      gemm_bt<4, 24, 2><<<320 * 2, 256, 0, stream>>>(
          Ob, wop + 196608, nullptr, bsum + 256, dec_w, logit, 0);
  }

  sigmoid_kernel<<<NPOS / 256, 256, 0, stream>>>(logit, dec_b, out);
}

// Round 11
// 372.209 us; speedup vs baseline: 1.7166x; 1.7166x over previous
//
#include <hip/hip_runtime.h>
#include <stdint.h>

typedef unsigned short u16;
typedef u16 u16x8 __attribute__((ext_vector_type(8)));
typedef __bf16 bf16x8 __attribute__((ext_vector_type(8)));
typedef float f32x4 __attribute__((ext_vector_type(4)));
typedef float f32x16 __attribute__((ext_vector_type(16)));

#define NE   256
#define NPOS 40960     // 32*64*4*5
#define QLD  768       // QKV row stride (seq only)

__device__ __forceinline__ float bf2f(u16 h) {
  union { unsigned u; float f; } c; c.u = ((unsigned)h) << 16; return c.f;
}
__device__ __forceinline__ u16 f2bf(float f) {
  union { float f; unsigned u; } c; c.f = f;
  unsigned u = c.u;
  return (u16)((u + 0x7FFFu + ((u >> 16) & 1u)) >> 16);
}
__device__ __forceinline__ unsigned pkbf(float a, float b) {
  unsigned r;
  asm("v_cvt_pk_bf16_f32 %0, %1, %2" : "=v"(r) : "v"(a), "v"(b));
  return r;
}
__device__ __forceinline__ void gll16(const void* g, void* l) {
  __builtin_amdgcn_global_load_lds(
      (const __attribute__((address_space(1))) void*)g,
      (__attribute__((address_space(3))) void*)l, 16, 0, 0);
}
template<int N> __device__ __forceinline__ void waitvm() {
  if constexpr (N == 0)       asm volatile("s_waitcnt vmcnt(0)"  ::: "memory");
  else if constexpr (N == 4)  asm volatile("s_waitcnt vmcnt(4)"  ::: "memory");
  else if constexpr (N == 6)  asm volatile("s_waitcnt vmcnt(6)"  ::: "memory");
  else if constexpr (N == 8)  asm volatile("s_waitcnt vmcnt(8)"  ::: "memory");
  else if constexpr (N == 12) asm volatile("s_waitcnt vmcnt(12)" ::: "memory");
}

// ---------------------------------------------------------------------------
// prep: xb[n][e] = bf16(x[b,s,e,h,w] + pos), n = ((b*64+s)*4+h)*5+w
// ---------------------------------------------------------------------------
__global__ __launch_bounds__(256) void prep_kernel(
    const float* __restrict__ x, const float* __restrict__ pos_s,
    const float* __restrict__ pos_h, const float* __restrict__ pos_w,
    u16* __restrict__ xb)
{
  __shared__ float Ls[256 * 21];
  const int bs = blockIdx.x;           // b*64+s
  const int s  = bs & 63;
  const int tid = threadIdx.x;
  const float* xp = x + (size_t)bs * 5120;
  for (int i = tid; i < 5120; i += 256) {
    int e = i / 20, hw = i % 20;
    int h = hw / 5, w = hw % 5;
    float v = xp[i] + pos_s[s * 256 + e] + pos_h[e * 4 + h] + pos_w[e * 5 + w];
    Ls[e * 21 + hw] = v;
  }
  __syncthreads();
  u16* op = xb + (size_t)bs * 20 * 256;
  for (int i = tid; i < 5120; i += 256) {
    int nl = i >> 8, e = i & 255;
    op[nl * 256 + e] = f2bf(Ls[e * 21 + nl]);
  }
}

// ---------------------------------------------------------------------------
// all weight packing in one dispatch
// ---------------------------------------------------------------------------
#define PK_T1 (6*768*256)
#define PK_T2 (2*256*768)
__global__ __launch_bounds__(256) void pack_all(
    const float* __restrict__ wq, const float* __restrict__ wkv,
    const float* __restrict__ wo, const float* __restrict__ wo_b,
    u16* __restrict__ wqp, u16* __restrict__ wop, float* __restrict__ bsum)
{
  int i = blockIdx.x * 256 + threadIdx.x;
  if (i < PK_T1) {
    int la = i / (768 * 256);
    int rem = i - la * (768 * 256);
    int r = rem >> 8, c = rem & 255;
    float v = (r < 256) ? wq[(size_t)la * 65536 + r * 256 + c] * 0.25f
                        : wkv[(size_t)la * 131072 + (r - 256) * 256 + c];
    wqp[i] = f2bf(v);
  } else if (i < PK_T1 + PK_T2) {
    int j = i - PK_T1;
    int l = j / 196608;
    int rem = j - l * 196608;
    int out = rem / 768, k = rem % 768;
    int a = k >> 8, in = k & 255;
    wop[j] = f2bf(wo[(size_t)(((l * 3 + a) * 256) + out) * 256 + in]);
  } else if (i < PK_T1 + PK_T2 + 512) {
    int j = i - PK_T1 - PK_T2;
    int l = j >> 8, c = j & 255;
    bsum[j] = wo_b[(l * 3 + 0) * 256 + c] + wo_b[(l * 3 + 1) * 256 + c]
            + wo_b[(l * 3 + 2) * 256 + c];
  }
}

// ---------------------------------------------------------------------------
// GEMM: C[M][N] = A[M][K] * B[N][K]^T   (A,B bf16; acc f32)
// 128x128 tile, triple-buffered LDS, 2-deep counted-vmcnt prefetch,
// XCD-chunked bijective swizzle (bn-fastest within chunk).
// MODE 0: store bf16 at ldc; 3: Cb = bf16(acc+bias); 4: fused decode partial
// ---------------------------------------------------------------------------
template<int MODE, int NKT, int NBN>
__global__ __launch_bounds__(256, 2) void gemm_bt(
    const u16* __restrict__ A, const u16* __restrict__ B,
    u16* __restrict__ Cb, const float* __restrict__ bias,
    const float* __restrict__ dw, float* __restrict__ logit,
    int ldc)
{
  constexpr int K   = NKT * 32;
  constexpr int BN  = 128;
  constexpr int NF  = BN / 32;
  constexpr int LPT = 2 + BN / 64;
  constexpr int ASZ = 128 * 32;
  constexpr int TSZ = (128 + BN) * 32;
  static_assert(NKT >= 2, "");

  __shared__ alignas(16) u16 smem[3 * TSZ];

  const int bid = blockIdx.x;
  const int cpx = gridDim.x >> 3;
  const int mapped = (bid & 7) * cpx + (bid >> 3);
  const int bm = mapped / NBN, bn = mapped % NBN;

  const int tid  = threadIdx.x;
  const int lane = tid & 63, w = tid >> 6;
  const int wr   = (w >> 1) * 64, wc = (w & 1) * (BN / 2);
  const int r16  = lane & 15, khi = lane >> 4;

  f32x4 acc[4][NF] = {};

  const u16* gA = A + (size_t)bm * 128 * K;
  const u16* gB = B + (size_t)bn * BN * K;

  auto STAGE = [&](int kt, int which) {
    u16* As = smem + which * TSZ;
    u16* Bs = As + ASZ;
    const u16* tA = gA + kt * 32;
    const u16* tB = gB + kt * 32;
    #pragma unroll
    for (int r = 0; r < 2; ++r) {
      int i = tid + r * 256;
      int row = i >> 2, seg = (i & 3) << 3;
      gll16(tA + (size_t)row * K + seg, (char*)As + i * 16);
    }
    #pragma unroll
    for (int r = 0; r < BN / 64; ++r) {
      int i = tid + r * 256;
      int row = i >> 2, seg = (i & 3) << 3;
      gll16(tB + (size_t)row * K + seg, (char*)Bs + i * 16);
    }
  };

  STAGE(0, 0);
  STAGE(1, 1);
  #pragma unroll
  for (int kt = 0; kt < NKT; ++kt) {
    const int cur = kt % 3;
    if (kt + 2 < NKT)      { STAGE(kt + 2, (kt + 2) % 3); waitvm<2 * LPT>(); }
    else if (kt + 1 < NKT) { waitvm<LPT>(); }
    else                   { waitvm<0>(); }
    __builtin_amdgcn_s_barrier();
    asm volatile("" ::: "memory");

    const u16* As = smem + cur * TSZ;
    const u16* Bs = As + ASZ;
    bf16x8 af[4], bfr[NF];
    #pragma unroll
    for (int m = 0; m < 4; ++m)
      af[m] = *(const bf16x8*)(As + (wr + m * 16 + r16) * 32 + khi * 8);
    #pragma unroll
    for (int n = 0; n < NF; ++n)
      bfr[n] = *(const bf16x8*)(Bs + (wc + n * 16 + r16) * 32 + khi * 8);
    #pragma unroll
    for (int m = 0; m < 4; ++m)
      #pragma unroll
      for (int n = 0; n < NF; ++n)
        acc[m][n] = __builtin_amdgcn_mfma_f32_16x16x32_bf16(af[m], bfr[n], acc[m][n], 0, 0, 0);

    asm volatile("" ::: "memory");
    __builtin_amdgcn_s_barrier();
  }

  const int row0 = bm * 128 + wr + khi * 4;
  const int col0 = bn * BN + wc + r16;

  if constexpr (MODE == 4) {
    float dwv[NF], bvv[NF];
    #pragma unroll
    for (int n = 0; n < NF; ++n) {
      int c = col0 + n * 16;
      dwv[n] = dw[c];
      bvv[n] = bias[c];
    }
    #pragma unroll
    for (int m = 0; m < 4; ++m) {
      #pragma unroll
      for (int j = 0; j < 4; ++j) {
        float p = 0.f;
        #pragma unroll
        for (int n = 0; n < NF; ++n) p += (acc[m][n][j] + bvv[n]) * dwv[n];
        p += __shfl_xor(p, 1);
        p += __shfl_xor(p, 2);
        p += __shfl_xor(p, 4);
        p += __shfl_xor(p, 8);
        if (r16 == 0) atomicAdd(&logit[row0 + m * 16 + j], p);
      }
    }
  } else {
    #pragma unroll
    for (int m = 0; m < 4; ++m) {
      #pragma unroll
      for (int n = 0; n < NF; ++n) {
        int c = col0 + n * 16;
        float bv = (MODE == 3) ? bias[c] : 0.f;
        #pragma unroll
        for (int j = 0; j < 4; ++j) {
          int r = row0 + m * 16 + j;
          Cb[(size_t)r * ldc + c] = f2bf(acc[m][n][j] + bv);
        }
      }
    }
  }
}

// ---------------------------------------------------------------------------
// seq-axis attention via MFMA. One wave = one (group g, head hd).
// QKV [NPOS][768] bf16 (q|k|v). Writes Ob cols 0..255 (ld 768).
// ---------------------------------------------------------------------------
__global__ __launch_bounds__(256) void attn_seq_mfma(
    const u16* __restrict__ QKV, u16* __restrict__ Ob)
{
  const int w = threadIdx.x >> 6, lane = threadIdx.x & 63;
  const int wid = blockIdx.x * 4 + w;
  const int hd = wid & 15, g = wid >> 4;          // g in [0,640)
  const int gb = g / 20, gr = g % 20;
  const int nbase = gb * 1280 + gr;               // + pos*20
  const int lo = lane & 31, hi = lane >> 5;

  bf16x8 kf[2], qf[2];
  #pragma unroll
  for (int t = 0; t < 2; ++t) {
    size_t r = (size_t)(nbase + (lo + 32 * t) * 20) * QLD;
    kf[t] = *(const bf16x8*)(QKV + r + 256 + hd * 16 + hi * 8);
    qf[t] = *(const bf16x8*)(QKV + r +       hd * 16 + hi * 8);
  }
  union { u16 a[8]; bf16x8 v; } vt[4];
  #pragma unroll
  for (int c = 0; c < 4; ++c)
    #pragma unroll
    for (int j = 0; j < 8; ++j)
      vt[c].a[j] = QKV[(size_t)(nbase + (c * 16 + hi * 8 + j) * 20) * QLD
                       + 512 + hd * 16 + lo];

  f32x16 s00 = {}, s10 = {}, s01 = {}, s11 = {};   // s[kt][qt]
  s00 = __builtin_amdgcn_mfma_f32_32x32x16_bf16(kf[0], qf[0], s00, 0, 0, 0);
  s10 = __builtin_amdgcn_mfma_f32_32x32x16_bf16(kf[1], qf[0], s10, 0, 0, 0);
  s01 = __builtin_amdgcn_mfma_f32_32x32x16_bf16(kf[0], qf[1], s01, 0, 0, 0);
  s11 = __builtin_amdgcn_mfma_f32_32x32x16_bf16(kf[1], qf[1], s11, 0, 0, 0);

  auto run_qt = [&](f32x16 t0, f32x16 t1, int qt) {
    float m = -1e30f;
    #pragma unroll
    for (int r = 0; r < 16; ++r) { m = fmaxf(m, t0[r]); m = fmaxf(m, t1[r]); }
    m = fmaxf(m, __shfl_xor(m, 32));
    const float C = 1.4426950408889634f;           // log2(e); 0.25 folded in wq
    float mc = m * C;
    float sum = 0.f;
    #pragma unroll
    for (int r = 0; r < 16; ++r) {
      float p0 = __builtin_amdgcn_exp2f(t0[r] * C - mc);
      float p1 = __builtin_amdgcn_exp2f(t1[r] * C - mc);
      t0[r] = p0; t1[r] = p1; sum += p0; sum += p1;
    }
    sum += __shfl_xor(sum, 32);
    float inv = __builtin_amdgcn_rcpf(sum);
    #pragma unroll
    for (int r = 0; r < 16; ++r) { t0[r] *= inv; t1[r] *= inv; }

    f32x16 oa = {};
    #pragma unroll
    for (int c = 0; c < 4; ++c) {
      const int rb = 8 * (c & 1);
      const f32x16& tt = (c < 2) ? t0 : t1;
      unsigned X0 = pkbf(tt[rb + 0], tt[rb + 1]);
      unsigned X1 = pkbf(tt[rb + 2], tt[rb + 3]);
      unsigned Y0 = pkbf(tt[rb + 4], tt[rb + 5]);
      unsigned Y1 = pkbf(tt[rb + 6], tt[rb + 7]);
      unsigned X0p = __shfl_xor((int)X0, 32), X1p = __shfl_xor((int)X1, 32);
      unsigned Y0p = __shfl_xor((int)Y0, 32), Y1p = __shfl_xor((int)Y1, 32);
      union { unsigned u[4]; bf16x8 v; } pf;
      pf.u[0] = hi ? Y0p : X0;
      pf.u[1] = hi ? Y1p : X1;
      pf.u[2] = hi ? Y0  : X0p;
      pf.u[3] = hi ? Y1  : X1p;
      oa = __builtin_amdgcn_mfma_f32_32x32x16_bf16(vt[c].v, pf.v, oa, 0, 0, 0);
    }
    unsigned P0 = pkbf(oa[0], oa[1]);
    unsigned P1 = pkbf(oa[2], oa[3]);
    unsigned P2 = pkbf(oa[4], oa[5]);
    unsigned P3 = pkbf(oa[6], oa[7]);
    unsigned sP0 = __shfl_xor((int)P0, 32), sP1 = __shfl_xor((int)P1, 32);
    unsigned sP2 = __shfl_xor((int)P2, 32), sP3 = __shfl_xor((int)P3, 32);
    union { unsigned u[4]; u16x8 v; } ov;
    ov.u[0] = hi ? sP2 : P0;
    ov.u[1] = hi ? sP3 : P1;
    ov.u[2] = hi ? P2  : sP0;
    ov.u[3] = hi ? P3  : sP1;
    u16* po = Ob + (size_t)(nbase + (qt * 32 + lo) * 20) * 768 + hd * 16 + hi * 8;
    *(u16x8*)po = ov.v;
  };
  run_qt(s00, s10, 0);
  run_qt(s01, s11, 1);
}

// ---------------------------------------------------------------------------
// fused H+W projection + attention. Block = 80 rows (4 planes), 320 thr.
// Per head: weights (48x256 bf16 = 24 KB) staged to LDS via global_load_lds
// with seg-XOR pre-swizzled SOURCE (LDS dest linear as HW requires); MFMA
// reads apply the same XOR -> b128-optimal bank spread. qkv tile in LDS bf16.
// Then per-(group,head) scalar attention. No QKV materialization to HBM.
// ---------------------------------------------------------------------------
__global__ __launch_bounds__(320) void fused_hw(
    const u16* __restrict__ xb, const u16* __restrict__ wqp_l,
    u16* __restrict__ Ob)
{
  __shared__ u16 qkv[80][776];                   // 124,160 B
  __shared__ alignas(16) u16 wlds[48 * 256];     //  24,576 B  (tot 148.7 KB)
  const int tid = threadIdx.x;
  const int w = tid >> 6, lane = tid & 63;
  const int n0 = blockIdx.x * 80;
  const int r16 = lane & 15, khi = lane >> 4;
  const int arow = n0 + w * 16 + r16;

  // A-frags: wave's 16 rows x K=256, reused across heads and axes
  bf16x8 af[8];
  #pragma unroll
  for (int ks = 0; ks < 8; ++ks)
    af[ks] = *(const bf16x8*)(xb + (size_t)arow * 256 + ks * 32 + khi * 8);

  for (int axis = 0; axis < 2; ++axis) {
    const u16* wb = wqp_l + (size_t)axis * 196608;

    // ---- per head: stage weights -> LDS, MFMA -> qkv LDS ----
    for (int hd = 0; hd < 16; ++hd) {
      __syncthreads();                 // prior wlds/qkv readers done
      for (int i = tid; i < 1536; i += 320) {
        int r = i >> 5, s = i & 31;                    // r: 0..47, s: 16B seg
        int gr = (r >> 4) * 256 + hd * 16 + (r & 15);  // global weight row
        int ss = s ^ (r & 7);                          // pre-swizzled source
        gll16(wb + (size_t)gr * 256 + ss * 8, (char*)wlds + i * 16);
      }
      waitvm<0>();
      __syncthreads();

      f32x4 acc[3] = {};
      #pragma unroll
      for (int nf = 0; nf < 3; ++nf) {
        #pragma unroll
        for (int ks = 0; ks < 8; ++ks) {
          int r = nf * 16 + r16;
          int phys = (4 * ks + khi) ^ (r16 & 7);
          bf16x8 bf = *(const bf16x8*)(wlds + (r * 32 + phys) * 8);
          acc[nf] = __builtin_amdgcn_mfma_f32_16x16x32_bf16(af[ks], bf, acc[nf], 0, 0, 0);
        }
      }
      #pragma unroll
      for (int nf = 0; nf < 3; ++nf)
        #pragma unroll
        for (int j = 0; j < 4; ++j)
          qkv[w * 16 + khi * 4 + j][nf * 256 + hd * 16 + r16] = f2bf(acc[nf][j]);
    }
    __syncthreads();

    // ---- attention phase ----
    const int T = axis ? 5 : 4;
    const int ng = axis ? 16 : 20;
    if (tid < ng * 16) {
      const int g = tid >> 4, hd = tid & 15;
      int rbase, rstp;
      if (axis == 0) { rbase = (g / 5) * 20 + (g % 5);     rstp = 5; }
      else           { rbase = (g / 4) * 20 + (g % 4) * 5; rstp = 1; }
      float kk[5][16];
      #pragma unroll
      for (int j = 0; j < 5; ++j) {
        if (j < T) {
          const u16* kp = &qkv[rbase + j * rstp][256 + hd * 16];
          u16x8 a0 = *(const u16x8*)kp, a1 = *(const u16x8*)(kp + 8);
          #pragma unroll
          for (int d = 0; d < 8; ++d) {
            kk[j][d] = bf2f(a0[d]); kk[j][d + 8] = bf2f(a1[d]);
          }
        }
      }
      for (int i = 0; i < T; ++i) {
        const int r = rbase + i * rstp;
        const u16* qp = &qkv[r][hd * 16];
        u16x8 q0 = *(const u16x8*)qp, q1 = *(const u16x8*)(qp + 8);
        float q[16];
        #pragma unroll
        for (int d = 0; d < 8; ++d) { q[d] = bf2f(q0[d]); q[d + 8] = bf2f(q1[d]); }
        float s[5], m = -1e30f;
        #pragma unroll
        for (int j = 0; j < 5; ++j) {
          if (j < T) {
            float a = 0.f;
            #pragma unroll
            for (int d = 0; d < 16; ++d) a += q[d] * kk[j][d];
            s[j] = a; m = fmaxf(m, a);
          }
        }
        float sum = 0.f, o[16];
        #pragma unroll
        for (int d = 0; d < 16; ++d) o[d] = 0.f;
        #pragma unroll
        for (int j = 0; j < 5; ++j) {
          if (j < T) {
            float pj = __expf(s[j] - m);
            sum += pj;
            const u16* vp = &qkv[rbase + j * rstp][512 + hd * 16];
            u16x8 v0 = *(const u16x8*)vp, v1 = *(const u16x8*)(vp + 8);
            #pragma unroll
            for (int d = 0; d < 8; ++d) {
              o[d] += pj * bf2f(v0[d]); o[d + 8] += pj * bf2f(v1[d]);
            }
          }
        }
        float inv = 1.0f / sum;
        u16x8 r0, r1;
        #pragma unroll
        for (int d = 0; d < 8; ++d) {
          r0[d] = f2bf(o[d] * inv); r1[d] = f2bf(o[d + 8] * inv);
        }
        u16* po = Ob + (size_t)(n0 + r) * 768 + 256 + axis * 256 + hd * 16;
        *(u16x8*)(po)     = r0;
        *(u16x8*)(po + 8) = r1;
      }
    }
  }
}

// ---------------------------------------------------------------------------
// final sigmoid over accumulated logits
// ---------------------------------------------------------------------------
__global__ __launch_bounds__(256) void sigmoid_kernel(
    const float* __restrict__ logit, const float* __restrict__ dec_b,
    float* __restrict__ out)
{
  int i = blockIdx.x * 256 + threadIdx.x;
  out[i] = 1.0f / (1.0f + __expf(-(logit[i] + dec_b[0])));
}

// ---------------------------------------------------------------------------
extern "C" void kernel_launch(void* const* d_in, const int* in_sizes, int n_in,
                              void* d_out, int out_size, void* d_ws, size_t ws_size,
                              hipStream_t stream) {
  const float* x     = (const float*)d_in[0];
  const float* pos_s = (const float*)d_in[1];
  const float* pos_h = (const float*)d_in[2];
  const float* pos_w = (const float*)d_in[3];
  const float* wq    = (const float*)d_in[4];   // (2,3,256,256)
  const float* wkv   = (const float*)d_in[5];   // (2,3,512,256)
  const float* wo_w  = (const float*)d_in[6];   // (2,3,256,256)
  const float* wo_b  = (const float*)d_in[7];   // (2,3,256)
  const float* dec_w = (const float*)d_in[8];   // (1,256)
  const float* dec_b = (const float*)d_in[9];   // (1,)
  float* out = (float*)d_out;

  char* ws = (char*)d_ws;
  u16*   xb    = (u16*)ws;                       // 20,971,520
  u16*   Ob    = (u16*)(ws + 20971520);          // 62,914,560
  u16*   QKV   = (u16*)(ws + 83886080);          // 40960*768*2 = 62,914,560
  u16*   wqp   = (u16*)(ws + 146800640);         // 2,359,296
  u16*   wop   = (u16*)(ws + 149159936);         // 786,432
  float* bsum  = (float*)(ws + 149946368);       // 2,048
  float* logit = (float*)(ws + 149948416);       // 163,840  (end ~150 MB)

  prep_kernel<<<2048, 256, 0, stream>>>(x, pos_s, pos_h, pos_w, xb);
  pack_all<<<(PK_T1 + PK_T2 + 512 + 255) / 256, 256, 0, stream>>>(
      wq, wkv, wo_w, wo_b, wqp, wop, bsum);
  hipMemsetAsync(logit, 0, NPOS * sizeof(float), stream);

  for (int l = 0; l < 2; ++l) {
    // seq axis: QKV (768 cols), then MFMA attention -> Ob cols 0..255
    gemm_bt<0, 8, 6><<<320 * 6, 256, 0, stream>>>(
        xb, wqp + (size_t)(l * 3) * 196608, QKV, nullptr, nullptr, nullptr, QLD);
    attn_seq_mfma<<<2560, 256, 0, stream>>>(QKV, Ob);
    // H+W axes fused: projection + attention -> Ob cols 256..767
    fused_hw<<<NPOS / 80, 320, 0, stream>>>(
        xb, wqp + (size_t)(l * 3 + 1) * 196608, Ob);
    // merged out-projection (K=768)
    if (l == 0)
      gemm_bt<3, 24, 2><<<320 * 2, 256, 0, stream>>>(
          Ob, wop, xb, bsum, nullptr, nullptr, 256);
    else
      gemm_bt<4, 24, 2><<<320 * 2, 256, 0, stream>>>(
          Ob, wop + 196608, nullptr, bsum + 256, dec_w, logit, 0);
  }

  sigmoid_kernel<<<NPOS / 256, 256, 0, stream>>>(logit, dec_b, out);
}

// Round 12
// 335.218 us; speedup vs baseline: 1.9060x; 1.1103x over previous
//
#include <hip/hip_runtime.h>
#include <stdint.h>

typedef unsigned short u16;
typedef u16 u16x8 __attribute__((ext_vector_type(8)));
typedef __bf16 bf16x8 __attribute__((ext_vector_type(8)));
typedef float f32x4 __attribute__((ext_vector_type(4)));
typedef float f32x16 __attribute__((ext_vector_type(16)));

#define NE   256
#define NPOS 40960     // 32*64*4*5
#define QLD  1536      // QKV row stride

__device__ __forceinline__ float bf2f(u16 h) {
  union { unsigned u; float f; } c; c.u = ((unsigned)h) << 16; return c.f;
}
__device__ __forceinline__ u16 f2bf(float f) {
  union { float f; unsigned u; } c; c.f = f;
  unsigned u = c.u;
  return (u16)((u + 0x7FFFu + ((u >> 16) & 1u)) >> 16);
}
__device__ __forceinline__ unsigned pkbf(float a, float b) {
  unsigned r;
  asm("v_cvt_pk_bf16_f32 %0, %1, %2" : "=v"(r) : "v"(a), "v"(b));
  return r;
}
__device__ __forceinline__ void gll16(const void* g, void* l) {
  __builtin_amdgcn_global_load_lds(
      (const __attribute__((address_space(1))) void*)g,
      (__attribute__((address_space(3))) void*)l, 16, 0, 0);
}
template<int N> __device__ __forceinline__ void waitvm() {
  if constexpr (N == 0)       asm volatile("s_waitcnt vmcnt(0)"  ::: "memory");
  else if constexpr (N == 2)  asm volatile("s_waitcnt vmcnt(2)"  ::: "memory");
  else if constexpr (N == 4)  asm volatile("s_waitcnt vmcnt(4)"  ::: "memory");
  else if constexpr (N == 6)  asm volatile("s_waitcnt vmcnt(6)"  ::: "memory");
  else if constexpr (N == 8)  asm volatile("s_waitcnt vmcnt(8)"  ::: "memory");
  else if constexpr (N == 12) asm volatile("s_waitcnt vmcnt(12)" ::: "memory");
}

// ---------------------------------------------------------------------------
// prep: xb[n][e] = bf16(x[b,s,e,h,w] + pos), n = ((b*64+s)*4+h)*5+w
// ---------------------------------------------------------------------------
__global__ __launch_bounds__(256) void prep_kernel(
    const float* __restrict__ x, const float* __restrict__ pos_s,
    const float* __restrict__ pos_h, const float* __restrict__ pos_w,
    u16* __restrict__ xb)
{
  __shared__ float Ls[256 * 21];
  const int bs = blockIdx.x;           // b*64+s
  const int s  = bs & 63;
  const int tid = threadIdx.x;
  const float* xp = x + (size_t)bs * 5120;
  for (int i = tid; i < 5120; i += 256) {
    int e = i / 20, hw = i % 20;
    int h = hw / 5, w = hw % 5;
    float v = xp[i] + pos_s[s * 256 + e] + pos_h[e * 4 + h] + pos_w[e * 5 + w];
    Ls[e * 21 + hw] = v;
  }
  __syncthreads();
  u16* op = xb + (size_t)bs * 20 * 256;
  for (int i = tid; i < 5120; i += 256) {
    int nl = i >> 8, e = i & 255;
    op[nl * 256 + e] = f2bf(Ls[e * 21 + nl]);
  }
}

// ---------------------------------------------------------------------------
// all weight packing in one dispatch
// ---------------------------------------------------------------------------
#define PK_T1 (6*768*256)
#define PK_T2 (2*256*768)
__global__ __launch_bounds__(256) void pack_all(
    const float* __restrict__ wq, const float* __restrict__ wkv,
    const float* __restrict__ wo, const float* __restrict__ wo_b,
    u16* __restrict__ wqp, u16* __restrict__ wop, float* __restrict__ bsum)
{
  int i = blockIdx.x * 256 + threadIdx.x;
  if (i < PK_T1) {
    int la = i / (768 * 256);
    int rem = i - la * (768 * 256);
    int r = rem >> 8, c = rem & 255;
    float v = (r < 256) ? wq[(size_t)la * 65536 + r * 256 + c] * 0.25f
                        : wkv[(size_t)la * 131072 + (r - 256) * 256 + c];
    wqp[i] = f2bf(v);
  } else if (i < PK_T1 + PK_T2) {
    int j = i - PK_T1;
    int l = j / 196608;
    int rem = j - l * 196608;
    int out = rem / 768, k = rem % 768;
    int a = k >> 8, in = k & 255;
    wop[j] = f2bf(wo[(size_t)(((l * 3 + a) * 256) + out) * 256 + in]);
  } else if (i < PK_T1 + PK_T2 + 512) {
    int j = i - PK_T1 - PK_T2;
    int l = j >> 8, c = j & 255;
    bsum[j] = wo_b[(l * 3 + 0) * 256 + c] + wo_b[(l * 3 + 1) * 256 + c]
            + wo_b[(l * 3 + 2) * 256 + c];
  }
}

// ---------------------------------------------------------------------------
// STREAM GEMM for skinny-K tall-M: C[M][N] = A[M][K] * B[N][K]^T, bf16 out.
// Block owns (bn, strip of TPB M-tiles). B panel (128 x K) staged to LDS
// ONCE (kt-major layout = proven read pattern); A double-buffered, pipeline
// runs continuously across tiles: 1 barrier + counted vmcnt(2) per k-step,
// drain only at the last step. Epilogue stores are force-drained by the
// next vmcnt(2) (conservative, correct). 80 KB LDS -> 2 blocks/CU.
// ---------------------------------------------------------------------------
template<int NKT, int NBN, int TPB>
__global__ __launch_bounds__(256, 2) void gemm_stream(
    const u16* __restrict__ A, const u16* __restrict__ B,
    u16* __restrict__ Cb, int ldc)
{
  constexpr int K     = NKT * 32;
  constexpr int NSTEP = NKT * TPB;
  __shared__ alignas(16) u16 Bs[128 * K];        // 64 KB @ K=256
  __shared__ alignas(16) u16 As[2][128 * 32];    // 16 KB

  const int nblk = gridDim.x;
  const int bid  = blockIdx.x;
  const int mapped = (bid & 7) * (nblk >> 3) + (bid >> 3);   // XCD-chunked
  const int strip = mapped / NBN, bn = mapped % NBN;         // strip-major/XCD
  const int bm0 = strip * TPB;

  const int tid  = threadIdx.x;
  const int lane = tid & 63, w = tid >> 6;
  const int wr   = (w >> 1) * 64, wc = (w & 1) * 64;
  const int r16  = lane & 15, khi = lane >> 4;

  const u16* gB = B + (size_t)bn * 128 * K;
  const u16* gA = A + (size_t)bm0 * 128 * K;

  // one-time B stage: 16B slot = kt*512 + row*4 + c  holds B[row][kt*32+c*8..)
  #pragma unroll
  for (int b = 0; b < K / 16; ++b) {
    int slot = tid + b * 256;                    // 0 .. 128*K/8-1
    int kt = slot >> 9, rem = slot & 511;
    int row = rem >> 2, c = rem & 3;
    gll16(gB + (size_t)row * K + kt * 32 + c * 8, (char*)Bs + slot * 16);
  }

  auto STAGE_A = [&](int g) {
    const int t = g / NKT, kt = g % NKT;
    const u16* tA = gA + (size_t)t * 128 * K + kt * 32;
    u16* dst = As[g & 1];
    #pragma unroll
    for (int r = 0; r < 2; ++r) {
      int i = tid + r * 256;
      int row = i >> 2, seg = (i & 3) << 3;
      gll16(tA + (size_t)row * K + seg, (char*)dst + i * 16);
    }
  };

  f32x4 acc[4][4] = {};
  STAGE_A(0);

  for (int t = 0; t < TPB; ++t) {
    #pragma unroll
    for (int kt = 0; kt < NKT; ++kt) {
      const int g = t * NKT + kt;
      __builtin_amdgcn_s_barrier();              // prev readers of As[g&1^1] done
      if (g + 1 < NSTEP) { STAGE_A(g + 1); waitvm<2>(); }
      else               { waitvm<0>(); }
      asm volatile("" ::: "memory");

      const u16* Ab = As[g & 1];
      const u16* Bk = Bs + kt * (128 * 32);
      bf16x8 af[4], bfr[4];
      #pragma unroll
      for (int m = 0; m < 4; ++m)
        af[m] = *(const bf16x8*)(Ab + (wr + m * 16 + r16) * 32 + khi * 8);
      #pragma unroll
      for (int n = 0; n < 4; ++n)
        bfr[n] = *(const bf16x8*)(Bk + (wc + n * 16 + r16) * 32 + khi * 8);
      #pragma unroll
      for (int m = 0; m < 4; ++m)
        #pragma unroll
        for (int n = 0; n < 4; ++n)
          acc[m][n] = __builtin_amdgcn_mfma_f32_16x16x32_bf16(af[m], bfr[n], acc[m][n], 0, 0, 0);
      asm volatile("" ::: "memory");
    }
    // epilogue for tile t (stores drain at next waitvm — no pipeline stall)
    const int row0 = (bm0 + t) * 128 + wr + khi * 4;
    const int col0 = bn * 128 + wc + r16;
    #pragma unroll
    for (int m = 0; m < 4; ++m)
      #pragma unroll
      for (int n = 0; n < 4; ++n)
        #pragma unroll
        for (int j = 0; j < 4; ++j) {
          Cb[(size_t)(row0 + m * 16 + j) * ldc + col0 + n * 16] = f2bf(acc[m][n][j]);
          acc[m][n][j] = 0.f;
        }
  }
}

// ---------------------------------------------------------------------------
// GEMM (2-phase, 128x128): used for the K=768 out-projections.
// MODE 3: Cb = bf16(acc+bias); 4: fused decode partial into logit
// ---------------------------------------------------------------------------
template<int MODE, int NKT, int NBN>
__global__ __launch_bounds__(256, 2) void gemm_bt(
    const u16* __restrict__ A, const u16* __restrict__ B,
    u16* __restrict__ Cb, const float* __restrict__ bias,
    const float* __restrict__ dw, float* __restrict__ logit,
    int ldc)
{
  constexpr int K   = NKT * 32;
  constexpr int BN  = 128;
  constexpr int NF  = BN / 32;
  constexpr int LPT = 2 + BN / 64;
  constexpr int ASZ = 128 * 32;
  constexpr int TSZ = (128 + BN) * 32;
  static_assert(NKT >= 2, "");

  __shared__ alignas(16) u16 smem[3 * TSZ];

  const int bid = blockIdx.x;
  const int cpx = gridDim.x >> 3;
  const int mapped = (bid & 7) * cpx + (bid >> 3);
  const int bm = mapped / NBN, bn = mapped % NBN;

  const int tid  = threadIdx.x;
  const int lane = tid & 63, w = tid >> 6;
  const int wr   = (w >> 1) * 64, wc = (w & 1) * (BN / 2);
  const int r16  = lane & 15, khi = lane >> 4;

  f32x4 acc[4][NF] = {};

  const u16* gA = A + (size_t)bm * 128 * K;
  const u16* gB = B + (size_t)bn * BN * K;

  auto STAGE = [&](int kt, int which) {
    u16* As = smem + which * TSZ;
    u16* Bs = As + ASZ;
    const u16* tA = gA + kt * 32;
    const u16* tB = gB + kt * 32;
    #pragma unroll
    for (int r = 0; r < 2; ++r) {
      int i = tid + r * 256;
      int row = i >> 2, seg = (i & 3) << 3;
      gll16(tA + (size_t)row * K + seg, (char*)As + i * 16);
    }
    #pragma unroll
    for (int r = 0; r < BN / 64; ++r) {
      int i = tid + r * 256;
      int row = i >> 2, seg = (i & 3) << 3;
      gll16(tB + (size_t)row * K + seg, (char*)Bs + i * 16);
    }
  };

  STAGE(0, 0);
  STAGE(1, 1);
  #pragma unroll
  for (int kt = 0; kt < NKT; ++kt) {
    const int cur = kt % 3;
    if (kt + 2 < NKT)      { STAGE(kt + 2, (kt + 2) % 3); waitvm<2 * LPT>(); }
    else if (kt + 1 < NKT) { waitvm<LPT>(); }
    else                   { waitvm<0>(); }
    __builtin_amdgcn_s_barrier();
    asm volatile("" ::: "memory");

    const u16* As = smem + cur * TSZ;
    const u16* Bs = As + ASZ;
    bf16x8 af[4], bfr[NF];
    #pragma unroll
    for (int m = 0; m < 4; ++m)
      af[m] = *(const bf16x8*)(As + (wr + m * 16 + r16) * 32 + khi * 8);
    #pragma unroll
    for (int n = 0; n < NF; ++n)
      bfr[n] = *(const bf16x8*)(Bs + (wc + n * 16 + r16) * 32 + khi * 8);
    #pragma unroll
    for (int m = 0; m < 4; ++m)
      #pragma unroll
      for (int n = 0; n < NF; ++n)
        acc[m][n] = __builtin_amdgcn_mfma_f32_16x16x32_bf16(af[m], bfr[n], acc[m][n], 0, 0, 0);

    asm volatile("" ::: "memory");
    __builtin_amdgcn_s_barrier();
  }

  const int row0 = bm * 128 + wr + khi * 4;
  const int col0 = bn * BN + wc + r16;

  if constexpr (MODE == 4) {
    float dwv[NF], bvv[NF];
    #pragma unroll
    for (int n = 0; n < NF; ++n) {
      int c = col0 + n * 16;
      dwv[n] = dw[c];
      bvv[n] = bias[c];
    }
    #pragma unroll
    for (int m = 0; m < 4; ++m) {
      #pragma unroll
      for (int j = 0; j < 4; ++j) {
        float p = 0.f;
        #pragma unroll
        for (int n = 0; n < NF; ++n) p += (acc[m][n][j] + bvv[n]) * dwv[n];
        p += __shfl_xor(p, 1);
        p += __shfl_xor(p, 2);
        p += __shfl_xor(p, 4);
        p += __shfl_xor(p, 8);
        if (r16 == 0) atomicAdd(&logit[row0 + m * 16 + j], p);
      }
    }
  } else {
    #pragma unroll
    for (int m = 0; m < 4; ++m) {
      #pragma unroll
      for (int n = 0; n < NF; ++n) {
        int c = col0 + n * 16;
        float bv = (MODE == 3) ? bias[c] : 0.f;
        #pragma unroll
        for (int j = 0; j < 4; ++j) {
          int r = row0 + m * 16 + j;
          Cb[(size_t)r * ldc + c] = f2bf(acc[m][n][j] + bv);
        }
      }
    }
  }
}

// ---------------------------------------------------------------------------
// seq-axis attention via MFMA. One wave = one (group g, head hd).
// QKV [NPOS][QLD] bf16 (q|k|v in cols 0..767). Writes Ob cols 0..255 (ld 768).
// ---------------------------------------------------------------------------
__global__ __launch_bounds__(256) void attn_seq_mfma(
    const u16* __restrict__ QKV, u16* __restrict__ Ob)
{
  const int w = threadIdx.x >> 6, lane = threadIdx.x & 63;
  const int wid = blockIdx.x * 4 + w;
  const int hd = wid & 15, g = wid >> 4;          // g in [0,640)
  const int gb = g / 20, gr = g % 20;
  const int nbase = gb * 1280 + gr;               // + pos*20
  const int lo = lane & 31, hi = lane >> 5;

  bf16x8 kf[2], qf[2];
  #pragma unroll
  for (int t = 0; t < 2; ++t) {
    size_t r = (size_t)(nbase + (lo + 32 * t) * 20) * QLD;
    kf[t] = *(const bf16x8*)(QKV + r + 256 + hd * 16 + hi * 8);
    qf[t] = *(const bf16x8*)(QKV + r +       hd * 16 + hi * 8);
  }
  union { u16 a[8]; bf16x8 v; } vt[4];
  #pragma unroll
  for (int c = 0; c < 4; ++c)
    #pragma unroll
    for (int j = 0; j < 8; ++j)
      vt[c].a[j] = QKV[(size_t)(nbase + (c * 16 + hi * 8 + j) * 20) * QLD
                       + 512 + hd * 16 + lo];

  f32x16 s00 = {}, s10 = {}, s01 = {}, s11 = {};   // s[kt][qt]
  s00 = __builtin_amdgcn_mfma_f32_32x32x16_bf16(kf[0], qf[0], s00, 0, 0, 0);
  s10 = __builtin_amdgcn_mfma_f32_32x32x16_bf16(kf[1], qf[0], s10, 0, 0, 0);
  s01 = __builtin_amdgcn_mfma_f32_32x32x16_bf16(kf[0], qf[1], s01, 0, 0, 0);
  s11 = __builtin_amdgcn_mfma_f32_32x32x16_bf16(kf[1], qf[1], s11, 0, 0, 0);

  auto run_qt = [&](f32x16 t0, f32x16 t1, int qt) {
    float m = -1e30f;
    #pragma unroll
    for (int r = 0; r < 16; ++r) { m = fmaxf(m, t0[r]); m = fmaxf(m, t1[r]); }
    m = fmaxf(m, __shfl_xor(m, 32));
    const float C = 1.4426950408889634f;           // log2(e); 0.25 folded in wq
    float mc = m * C;
    float sum = 0.f;
    #pragma unroll
    for (int r = 0; r < 16; ++r) {
      float p0 = __builtin_amdgcn_exp2f(t0[r] * C - mc);
      float p1 = __builtin_amdgcn_exp2f(t1[r] * C - mc);
      t0[r] = p0; t1[r] = p1; sum += p0; sum += p1;
    }
    sum += __shfl_xor(sum, 32);
    float inv = __builtin_amdgcn_rcpf(sum);
    #pragma unroll
    for (int r = 0; r < 16; ++r) { t0[r] *= inv; t1[r] *= inv; }

    f32x16 oa = {};
    #pragma unroll
    for (int c = 0; c < 4; ++c) {
      const int rb = 8 * (c & 1);
      const f32x16& tt = (c < 2) ? t0 : t1;
      unsigned X0 = pkbf(tt[rb + 0], tt[rb + 1]);
      unsigned X1 = pkbf(tt[rb + 2], tt[rb + 3]);
      unsigned Y0 = pkbf(tt[rb + 4], tt[rb + 5]);
      unsigned Y1 = pkbf(tt[rb + 6], tt[rb + 7]);
      unsigned X0p = __shfl_xor((int)X0, 32), X1p = __shfl_xor((int)X1, 32);
      unsigned Y0p = __shfl_xor((int)Y0, 32), Y1p = __shfl_xor((int)Y1, 32);
      union { unsigned u[4]; bf16x8 v; } pf;
      pf.u[0] = hi ? Y0p : X0;
      pf.u[1] = hi ? Y1p : X1;
      pf.u[2] = hi ? Y0  : X0p;
      pf.u[3] = hi ? Y1  : X1p;
      oa = __builtin_amdgcn_mfma_f32_32x32x16_bf16(vt[c].v, pf.v, oa, 0, 0, 0);
    }
    unsigned P0 = pkbf(oa[0], oa[1]);
    unsigned P1 = pkbf(oa[2], oa[3]);
    unsigned P2 = pkbf(oa[4], oa[5]);
    unsigned P3 = pkbf(oa[6], oa[7]);
    unsigned sP0 = __shfl_xor((int)P0, 32), sP1 = __shfl_xor((int)P1, 32);
    unsigned sP2 = __shfl_xor((int)P2, 32), sP3 = __shfl_xor((int)P3, 32);
    union { unsigned u[4]; u16x8 v; } ov;
    ov.u[0] = hi ? sP2 : P0;
    ov.u[1] = hi ? sP3 : P1;
    ov.u[2] = hi ? P2  : sP0;
    ov.u[3] = hi ? P3  : sP1;
    u16* po = Ob + (size_t)(nbase + (qt * 32 + lo) * 20) * 768 + hd * 16 + hi * 8;
    *(u16x8*)po = ov.v;
  };
  run_qt(s00, s10, 0);
  run_qt(s01, s11, 1);
}

// ---------------------------------------------------------------------------
// H (T=4, stride 5) and W (T=5, stride 1) attention, one thread per (n, head)
// ---------------------------------------------------------------------------
template<int T>
__device__ __forceinline__ void attn1(
    const u16* __restrict__ QKV, int n, int base, int stp, int hd,
    u16* __restrict__ po)
{
  const u16* qp = QKV + (size_t)n * QLD + hd * 16;
  u16x8 q0 = *(const u16x8*)(qp), q1 = *(const u16x8*)(qp + 8);
  float q[16];
  #pragma unroll
  for (int d = 0; d < 8; ++d) { q[d] = bf2f(q0[d]); q[d + 8] = bf2f(q1[d]); }

  float s[T];
  float m = -1e30f;
  #pragma unroll
  for (int j = 0; j < T; ++j) {
    const u16* kp = QKV + (size_t)(base + j * stp) * QLD + 256 + hd * 16;
    u16x8 k0 = *(const u16x8*)(kp), k1 = *(const u16x8*)(kp + 8);
    float a = 0.f;
    #pragma unroll
    for (int d = 0; d < 8; ++d) a += q[d] * bf2f(k0[d]) + q[d + 8] * bf2f(k1[d]);
    s[j] = a;
    m = fmaxf(m, a);
  }
  float sum = 0.f;
  float o[16];
  #pragma unroll
  for (int d = 0; d < 16; ++d) o[d] = 0.f;
  #pragma unroll
  for (int j = 0; j < T; ++j) {
    float pj = __expf(s[j] - m);
    sum += pj;
    const u16* vp = QKV + (size_t)(base + j * stp) * QLD + 512 + hd * 16;
    u16x8 w0 = *(const u16x8*)(vp), w1 = *(const u16x8*)(vp + 8);
    #pragma unroll
    for (int d = 0; d < 8; ++d) { o[d] += pj * bf2f(w0[d]); o[d + 8] += pj * bf2f(w1[d]); }
  }
  float inv = 1.0f / sum;
  u16x8 r0, r1;
  #pragma unroll
  for (int d = 0; d < 8; ++d) { r0[d] = f2bf(o[d] * inv); r1[d] = f2bf(o[d + 8] * inv); }
  *(u16x8*)(po)     = r0;
  *(u16x8*)(po + 8) = r1;
}

__global__ __launch_bounds__(256) void attn_hw(
    const u16* __restrict__ QKV, u16* __restrict__ Ob)
{
  const int tg = blockIdx.x * 256 + threadIdx.x;   // n*16 + hd
  const int hd = tg & 15, n = tg >> 4;
  int h  = (n % 20) / 5;
  int w5 = n % 5;
  attn1<4>(QKV,       n, n - h * 5, 5, hd, Ob + (size_t)n * 768 + 256 + hd * 16);
  attn1<5>(QKV + 768, n, n - w5,    1, hd, Ob + (size_t)n * 768 + 512 + hd * 16);
}

// ---------------------------------------------------------------------------
// final sigmoid over accumulated logits
// ---------------------------------------------------------------------------
__global__ __launch_bounds__(256) void sigmoid_kernel(
    const float* __restrict__ logit, const float* __restrict__ dec_b,
    float* __restrict__ out)
{
  int i = blockIdx.x * 256 + threadIdx.x;
  out[i] = 1.0f / (1.0f + __expf(-(logit[i] + dec_b[0])));
}

// ---------------------------------------------------------------------------
extern "C" void kernel_launch(void* const* d_in, const int* in_sizes, int n_in,
                              void* d_out, int out_size, void* d_ws, size_t ws_size,
                              hipStream_t stream) {
  const float* x     = (const float*)d_in[0];
  const float* pos_s = (const float*)d_in[1];
  const float* pos_h = (const float*)d_in[2];
  const float* pos_w = (const float*)d_in[3];
  const float* wq    = (const float*)d_in[4];   // (2,3,256,256)
  const float* wkv   = (const float*)d_in[5];   // (2,3,512,256)
  const float* wo_w  = (const float*)d_in[6];   // (2,3,256,256)
  const float* wo_b  = (const float*)d_in[7];   // (2,3,256)
  const float* dec_w = (const float*)d_in[8];   // (1,256)
  const float* dec_b = (const float*)d_in[9];   // (1,)
  float* out = (float*)d_out;

  char* ws = (char*)d_ws;
  u16*   xb    = (u16*)ws;                       // 20,971,520
  u16*   Ob    = (u16*)(ws + 20971520);          // 62,914,560
  u16*   QKV   = (u16*)(ws + 83886080);          // 40960*1536*2 = 125,829,120
  u16*   wqp   = (u16*)(ws + 209715200);         // 2,359,296
  u16*   wop   = (u16*)(ws + 212074496);         // 786,432
  float* bsum  = (float*)(ws + 212860928);       // 2,048
  float* logit = (float*)(ws + 212862976);       // 163,840  (end ~213 MB)

  prep_kernel<<<2048, 256, 0, stream>>>(x, pos_s, pos_h, pos_w, xb);
  pack_all<<<(PK_T1 + PK_T2 + 512 + 255) / 256, 256, 0, stream>>>(
      wq, wkv, wo_w, wo_b, wqp, wop, bsum);
  hipMemsetAsync(logit, 0, NPOS * sizeof(float), stream);

  for (int l = 0; l < 2; ++l) {
    // seq axis: QKV cols 0..767 (ldc 1536), stream GEMM, MFMA attention
    gemm_stream<8, 6, 4><<<480, 256, 0, stream>>>(
        xb, wqp + (size_t)(l * 3) * 196608, QKV, QLD);
    attn_seq_mfma<<<2560, 256, 0, stream>>>(QKV, Ob);
    // H+W axes: one N=1536 stream GEMM, one fused attention
    gemm_stream<8, 12, 4><<<960, 256, 0, stream>>>(
        xb, wqp + (size_t)(l * 3 + 1) * 196608, QKV, QLD);
    attn_hw<<<2560, 256, 0, stream>>>(QKV, Ob);
    // merged out-projection (K=768)
    if (l == 0)
      gemm_bt<3, 24, 2><<<320 * 2, 256, 0, stream>>>(
          Ob, wop, xb, bsum, nullptr, nullptr, 256);
    else
      gemm_bt<4, 24, 2><<<320 * 2, 256, 0, stream>>>(
          Ob, wop + 196608, nullptr, bsum + 256, dec_w, logit, 0);
  }

  sigmoid_kernel<<<NPOS / 256, 256, 0, stream>>>(logit, dec_b, out);
}

// Round 13
// 324.224 us; speedup vs baseline: 1.9706x; 1.0339x over previous
//
#include <hip/hip_runtime.h>
#include <stdint.h>

typedef unsigned short u16;
typedef u16 u16x8 __attribute__((ext_vector_type(8)));
typedef __bf16 bf16x8 __attribute__((ext_vector_type(8)));
typedef float f32x4 __attribute__((ext_vector_type(4)));
typedef float f32x16 __attribute__((ext_vector_type(16)));

#define NE   256
#define NPOS 40960     // 32*64*4*5
#define QLD  2304      // QKV row stride: [seq q|k|v][H q|k|v][W q|k|v]

__device__ __forceinline__ float bf2f(u16 h) {
  union { unsigned u; float f; } c; c.u = ((unsigned)h) << 16; return c.f;
}
__device__ __forceinline__ u16 f2bf(float f) {
  union { float f; unsigned u; } c; c.f = f;
  unsigned u = c.u;
  return (u16)((u + 0x7FFFu + ((u >> 16) & 1u)) >> 16);
}
__device__ __forceinline__ unsigned pkbf(float a, float b) {
  unsigned r;
  asm("v_cvt_pk_bf16_f32 %0, %1, %2" : "=v"(r) : "v"(a), "v"(b));
  return r;
}
__device__ __forceinline__ void gll16(const void* g, void* l) {
  __builtin_amdgcn_global_load_lds(
      (const __attribute__((address_space(1))) void*)g,
      (__attribute__((address_space(3))) void*)l, 16, 0, 0);
}
template<int N> __device__ __forceinline__ void waitvm() {
  if constexpr (N == 0)       asm volatile("s_waitcnt vmcnt(0)"  ::: "memory");
  else if constexpr (N == 2)  asm volatile("s_waitcnt vmcnt(2)"  ::: "memory");
  else if constexpr (N == 4)  asm volatile("s_waitcnt vmcnt(4)"  ::: "memory");
  else if constexpr (N == 8)  asm volatile("s_waitcnt vmcnt(8)"  ::: "memory");
}

// ---------------------------------------------------------------------------
// prep: xb[n][e] = bf16(x[b,s,e,h,w] + pos), n = ((b*64+s)*4+h)*5+w
// ---------------------------------------------------------------------------
__global__ __launch_bounds__(256) void prep_kernel(
    const float* __restrict__ x, const float* __restrict__ pos_s,
    const float* __restrict__ pos_h, const float* __restrict__ pos_w,
    u16* __restrict__ xb)
{
  __shared__ float Ls[256 * 21];
  const int bs = blockIdx.x;           // b*64+s
  const int s  = bs & 63;
  const int tid = threadIdx.x;
  const float* xp = x + (size_t)bs * 5120;
  for (int i = tid; i < 5120; i += 256) {
    int e = i / 20, hw = i % 20;
    int h = hw / 5, w = hw % 5;
    float v = xp[i] + pos_s[s * 256 + e] + pos_h[e * 4 + h] + pos_w[e * 5 + w];
    Ls[e * 21 + hw] = v;
  }
  __syncthreads();
  u16* op = xb + (size_t)bs * 20 * 256;
  for (int i = tid; i < 5120; i += 256) {
    int nl = i >> 8, e = i & 255;
    op[nl * 256 + e] = f2bf(Ls[e * 21 + nl]);
  }
}

// ---------------------------------------------------------------------------
// all weight packing in one dispatch
// ---------------------------------------------------------------------------
#define PK_T1 (6*768*256)
#define PK_T2 (2*256*768)
__global__ __launch_bounds__(256) void pack_all(
    const float* __restrict__ wq, const float* __restrict__ wkv,
    const float* __restrict__ wo, const float* __restrict__ wo_b,
    u16* __restrict__ wqp, u16* __restrict__ wop, float* __restrict__ bsum)
{
  int i = blockIdx.x * 256 + threadIdx.x;
  if (i < PK_T1) {
    int la = i / (768 * 256);
    int rem = i - la * (768 * 256);
    int r = rem >> 8, c = rem & 255;
    float v = (r < 256) ? wq[(size_t)la * 65536 + r * 256 + c] * 0.25f
                        : wkv[(size_t)la * 131072 + (r - 256) * 256 + c];
    wqp[i] = f2bf(v);
  } else if (i < PK_T1 + PK_T2) {
    int j = i - PK_T1;
    int l = j / 196608;
    int rem = j - l * 196608;
    int out = rem / 768, k = rem % 768;
    int a = k >> 8, in = k & 255;
    wop[j] = f2bf(wo[(size_t)(((l * 3 + a) * 256) + out) * 256 + in]);
  } else if (i < PK_T1 + PK_T2 + 512) {
    int j = i - PK_T1 - PK_T2;
    int l = j >> 8, c = j & 255;
    bsum[j] = wo_b[(l * 3 + 0) * 256 + c] + wo_b[(l * 3 + 1) * 256 + c]
            + wo_b[(l * 3 + 2) * 256 + c];
  }
}

// ---------------------------------------------------------------------------
// STREAM GEMM: C[M][N] = A[M][K]*B[N][K]^T, bf16 out at ldc.
// B panel staged ONCE (kt-major); A double-buffered; continuous pipeline.
// Seg-XOR bank swizzle (rule #21): LDS dest linear, SOURCE seg permuted by
// s^((row>>1)&3); read applies same XOR (per-thread constant since all
// fragment rows = r16 mod 16)  ->  2-way banks (free) instead of 8-way.
// ---------------------------------------------------------------------------
template<int NKT, int NBN, int TPB>
__global__ __launch_bounds__(256, 2) void gemm_stream(
    const u16* __restrict__ A, const u16* __restrict__ B,
    u16* __restrict__ Cb, int ldc)
{
  constexpr int K     = NKT * 32;
  constexpr int NSTEP = NKT * TPB;
  __shared__ alignas(16) u16 Bs[128 * K];        // 64 KB @ K=256
  __shared__ alignas(16) u16 As[2][128 * 32];    // 16 KB

  const int nblk = gridDim.x;
  const int bid  = blockIdx.x;
  const int mapped = (bid & 7) * (nblk >> 3) + (bid >> 3);   // XCD-chunked
  const int strip = mapped / NBN, bn = mapped % NBN;
  const int bm0 = strip * TPB;

  const int tid  = threadIdx.x;
  const int lane = tid & 63, w = tid >> 6;
  const int wr   = (w >> 1) * 64, wc = (w & 1) * 64;
  const int r16  = lane & 15, khi = lane >> 4;
  const int pofs = (khi ^ ((r16 >> 1) & 3)) * 8;   // swizzled seg offset (u16)

  const u16* gB = B + (size_t)bn * 128 * K;
  const u16* gA = A + (size_t)bm0 * 128 * K;

  // one-time B stage, kt-major, seg-swizzled source
  #pragma unroll
  for (int b = 0; b < K / 16; ++b) {
    int slot = tid + b * 256;                    // 0 .. 128*K/8-1
    int kt = slot >> 9, rem = slot & 511;
    int row = rem >> 2, c = rem & 3;
    int cs = c ^ ((row >> 1) & 3);
    gll16(gB + (size_t)row * K + kt * 32 + cs * 8, (char*)Bs + slot * 16);
  }

  auto STAGE_A = [&](int g) {
    const int t = g / NKT, kt = g % NKT;
    const u16* tA = gA + (size_t)t * 128 * K + kt * 32;
    u16* dst = As[g & 1];
    #pragma unroll
    for (int r = 0; r < 2; ++r) {
      int i = tid + r * 256;
      int row = i >> 2, s = i & 3;
      int ss = s ^ ((row >> 1) & 3);
      gll16(tA + (size_t)row * K + ss * 8, (char*)dst + i * 16);
    }
  };

  f32x4 acc[4][4] = {};
  STAGE_A(0);

  for (int t = 0; t < TPB; ++t) {
    #pragma unroll
    for (int kt = 0; kt < NKT; ++kt) {
      const int g = t * NKT + kt;
      __builtin_amdgcn_s_barrier();
      if (g + 1 < NSTEP) { STAGE_A(g + 1); waitvm<2>(); }
      else               { waitvm<0>(); }
      asm volatile("" ::: "memory");

      const u16* Ab = As[g & 1];
      const u16* Bk = Bs + kt * (128 * 32);
      bf16x8 af[4], bfr[4];
      #pragma unroll
      for (int m = 0; m < 4; ++m)
        af[m] = *(const bf16x8*)(Ab + (wr + m * 16 + r16) * 32 + pofs);
      #pragma unroll
      for (int n = 0; n < 4; ++n)
        bfr[n] = *(const bf16x8*)(Bk + (wc + n * 16 + r16) * 32 + pofs);
      #pragma unroll
      for (int m = 0; m < 4; ++m)
        #pragma unroll
        for (int n = 0; n < 4; ++n)
          acc[m][n] = __builtin_amdgcn_mfma_f32_16x16x32_bf16(af[m], bfr[n], acc[m][n], 0, 0, 0);
      asm volatile("" ::: "memory");
    }
    const int row0 = (bm0 + t) * 128 + wr + khi * 4;
    const int col0 = bn * 128 + wc + r16;
    #pragma unroll
    for (int m = 0; m < 4; ++m)
      #pragma unroll
      for (int n = 0; n < 4; ++n)
        #pragma unroll
        for (int j = 0; j < 4; ++j) {
          Cb[(size_t)(row0 + m * 16 + j) * ldc + col0 + n * 16] = f2bf(acc[m][n][j]);
          acc[m][n][j] = 0.f;
        }
  }
}

// ---------------------------------------------------------------------------
// out-projection GEMM (K=768): A rows gathered from QKV's three O-slots
// (logical col k -> phys (k>>8)*768 + (k&255), row stride QLD). Swizzled LDS.
// MODE 3: Cb = bf16(acc+bias); 4: fused decode partial into logit
// ---------------------------------------------------------------------------
template<int MODE, int NKT, int NBN>
__global__ __launch_bounds__(256, 2) void gemm_bt(
    const u16* __restrict__ A, const u16* __restrict__ B,
    u16* __restrict__ Cb, const float* __restrict__ bias,
    const float* __restrict__ dw, float* __restrict__ logit,
    int ldc)
{
  constexpr int K   = NKT * 32;
  constexpr int TSZ = 256 * 32;
  __shared__ alignas(16) u16 smem[3 * TSZ];

  const int bid = blockIdx.x;
  const int cpx = gridDim.x >> 3;
  const int mapped = (bid & 7) * cpx + (bid >> 3);
  const int bm = mapped / NBN, bn = mapped % NBN;

  const int tid  = threadIdx.x;
  const int lane = tid & 63, w = tid >> 6;
  const int wr   = (w >> 1) * 64, wc = (w & 1) * 64;
  const int r16  = lane & 15, khi = lane >> 4;
  const int pofs = (khi ^ ((r16 >> 1) & 3)) * 8;

  f32x4 acc[4][4] = {};

  const u16* gA = A + (size_t)bm * 128 * QLD;
  const u16* gB = B + (size_t)bn * 128 * K;

  auto STAGE = [&](int kt, int which) {
    u16* As = smem + which * TSZ;
    u16* Bsl = As + 128 * 32;
    #pragma unroll
    for (int r = 0; r < 2; ++r) {
      int i = tid + r * 256;
      int row = i >> 2, s = i & 3;
      int col = kt * 32 + (s ^ ((row >> 1) & 3)) * 8;      // logical 0..767
      int phys = (col >> 8) * 768 + (col & 255);
      gll16(gA + (size_t)row * QLD + phys, (char*)As + i * 16);
    }
    #pragma unroll
    for (int r = 0; r < 2; ++r) {
      int i = tid + r * 256;
      int row = i >> 2, s = i & 3;
      int ss = s ^ ((row >> 1) & 3);
      gll16(gB + (size_t)row * K + kt * 32 + ss * 8, (char*)Bsl + i * 16);
    }
  };

  STAGE(0, 0);
  STAGE(1, 1);
  #pragma unroll
  for (int kt = 0; kt < NKT; ++kt) {
    const int cur = kt % 3;
    if (kt + 2 < NKT)      { STAGE(kt + 2, (kt + 2) % 3); waitvm<8>(); }
    else if (kt + 1 < NKT) { waitvm<4>(); }
    else                   { waitvm<0>(); }
    __builtin_amdgcn_s_barrier();
    asm volatile("" ::: "memory");

    const u16* As = smem + cur * TSZ;
    const u16* Bsl = As + 128 * 32;
    bf16x8 af[4], bfr[4];
    #pragma unroll
    for (int m = 0; m < 4; ++m)
      af[m] = *(const bf16x8*)(As + (wr + m * 16 + r16) * 32 + pofs);
    #pragma unroll
    for (int n = 0; n < 4; ++n)
      bfr[n] = *(const bf16x8*)(Bsl + (wc + n * 16 + r16) * 32 + pofs);
    #pragma unroll
    for (int m = 0; m < 4; ++m)
      #pragma unroll
      for (int n = 0; n < 4; ++n)
        acc[m][n] = __builtin_amdgcn_mfma_f32_16x16x32_bf16(af[m], bfr[n], acc[m][n], 0, 0, 0);

    asm volatile("" ::: "memory");
    __builtin_amdgcn_s_barrier();
  }

  const int row0 = bm * 128 + wr + khi * 4;
  const int col0 = bn * 128 + wc + r16;

  if constexpr (MODE == 4) {
    float dwv[4], bvv[4];
    #pragma unroll
    for (int n = 0; n < 4; ++n) {
      int c = col0 + n * 16;
      dwv[n] = dw[c];
      bvv[n] = bias[c];
    }
    #pragma unroll
    for (int m = 0; m < 4; ++m) {
      #pragma unroll
      for (int j = 0; j < 4; ++j) {
        float p = 0.f;
        #pragma unroll
        for (int n = 0; n < 4; ++n) p += (acc[m][n][j] + bvv[n]) * dwv[n];
        p += __shfl_xor(p, 1);
        p += __shfl_xor(p, 2);
        p += __shfl_xor(p, 4);
        p += __shfl_xor(p, 8);
        if (r16 == 0) atomicAdd(&logit[row0 + m * 16 + j], p);
      }
    }
  } else {
    #pragma unroll
    for (int m = 0; m < 4; ++m) {
      #pragma unroll
      for (int n = 0; n < 4; ++n) {
        int c = col0 + n * 16;
        float bv = bias[c];
        #pragma unroll
        for (int j = 0; j < 4; ++j) {
          int r = row0 + m * 16 + j;
          Cb[(size_t)r * ldc + c] = f2bf(acc[m][n][j] + bv);
        }
      }
    }
  }
}

// ---------------------------------------------------------------------------
// seq-axis attention via MFMA. One wave = one (group, head). In-place:
// writes O over its own q-slot (cols hd*16.. of seq block) — q is private
// to this wave and fully read before any write.
// ---------------------------------------------------------------------------
__global__ __launch_bounds__(256) void attn_seq_mfma(u16* __restrict__ QKV)
{
  const int w = threadIdx.x >> 6, lane = threadIdx.x & 63;
  const int wid = blockIdx.x * 4 + w;
  const int hd = wid & 15, g = wid >> 4;          // g in [0,640)
  const int gb = g / 20, gr = g % 20;
  const int nbase = gb * 1280 + gr;               // + pos*20
  const int lo = lane & 31, hi = lane >> 5;

  bf16x8 kf[2], qf[2];
  #pragma unroll
  for (int t = 0; t < 2; ++t) {
    size_t r = (size_t)(nbase + (lo + 32 * t) * 20) * QLD;
    kf[t] = *(const bf16x8*)(QKV + r + 256 + hd * 16 + hi * 8);
    qf[t] = *(const bf16x8*)(QKV + r +       hd * 16 + hi * 8);
  }
  union { u16 a[8]; bf16x8 v; } vt[4];
  #pragma unroll
  for (int c = 0; c < 4; ++c)
    #pragma unroll
    for (int j = 0; j < 8; ++j)
      vt[c].a[j] = QKV[(size_t)(nbase + (c * 16 + hi * 8 + j) * 20) * QLD
                       + 512 + hd * 16 + lo];

  f32x16 s00 = {}, s10 = {}, s01 = {}, s11 = {};
  s00 = __builtin_amdgcn_mfma_f32_32x32x16_bf16(kf[0], qf[0], s00, 0, 0, 0);
  s10 = __builtin_amdgcn_mfma_f32_32x32x16_bf16(kf[1], qf[0], s10, 0, 0, 0);
  s01 = __builtin_amdgcn_mfma_f32_32x32x16_bf16(kf[0], qf[1], s01, 0, 0, 0);
  s11 = __builtin_amdgcn_mfma_f32_32x32x16_bf16(kf[1], qf[1], s11, 0, 0, 0);

  auto run_qt = [&](f32x16 t0, f32x16 t1, int qt) {
    float m = -1e30f;
    #pragma unroll
    for (int r = 0; r < 16; ++r) { m = fmaxf(m, t0[r]); m = fmaxf(m, t1[r]); }
    m = fmaxf(m, __shfl_xor(m, 32));
    const float C = 1.4426950408889634f;
    float mc = m * C;
    float sum = 0.f;
    #pragma unroll
    for (int r = 0; r < 16; ++r) {
      float p0 = __builtin_amdgcn_exp2f(t0[r] * C - mc);
      float p1 = __builtin_amdgcn_exp2f(t1[r] * C - mc);
      t0[r] = p0; t1[r] = p1; sum += p0; sum += p1;
    }
    sum += __shfl_xor(sum, 32);
    float inv = __builtin_amdgcn_rcpf(sum);
    #pragma unroll
    for (int r = 0; r < 16; ++r) { t0[r] *= inv; t1[r] *= inv; }

    f32x16 oa = {};
    #pragma unroll
    for (int c = 0; c < 4; ++c) {
      const int rb = 8 * (c & 1);
      const f32x16& tt = (c < 2) ? t0 : t1;
      unsigned X0 = pkbf(tt[rb + 0], tt[rb + 1]);
      unsigned X1 = pkbf(tt[rb + 2], tt[rb + 3]);
      unsigned Y0 = pkbf(tt[rb + 4], tt[rb + 5]);
      unsigned Y1 = pkbf(tt[rb + 6], tt[rb + 7]);
      unsigned X0p = __shfl_xor((int)X0, 32), X1p = __shfl_xor((int)X1, 32);
      unsigned Y0p = __shfl_xor((int)Y0, 32), Y1p = __shfl_xor((int)Y1, 32);
      union { unsigned u[4]; bf16x8 v; } pf;
      pf.u[0] = hi ? Y0p : X0;
      pf.u[1] = hi ? Y1p : X1;
      pf.u[2] = hi ? Y0  : X0p;
      pf.u[3] = hi ? Y1  : X1p;
      oa = __builtin_amdgcn_mfma_f32_32x32x16_bf16(vt[c].v, pf.v, oa, 0, 0, 0);
    }
    unsigned P0 = pkbf(oa[0], oa[1]);
    unsigned P1 = pkbf(oa[2], oa[3]);
    unsigned P2 = pkbf(oa[4], oa[5]);
    unsigned P3 = pkbf(oa[6], oa[7]);
    unsigned sP0 = __shfl_xor((int)P0, 32), sP1 = __shfl_xor((int)P1, 32);
    unsigned sP2 = __shfl_xor((int)P2, 32), sP3 = __shfl_xor((int)P3, 32);
    union { unsigned u[4]; u16x8 v; } ov;
    ov.u[0] = hi ? sP2 : P0;
    ov.u[1] = hi ? sP3 : P1;
    ov.u[2] = hi ? P2  : sP0;
    ov.u[3] = hi ? P3  : sP1;
    u16* po = QKV + (size_t)(nbase + (qt * 32 + lo) * 20) * QLD + hd * 16 + hi * 8;
    *(u16x8*)po = ov.v;
  };
  run_qt(s00, s10, 0);
  run_qt(s01, s11, 1);
}

// ---------------------------------------------------------------------------
// H (T=4, stride 5) and W (T=5, stride 1) attention, thread per (n, head).
// In-place: O written over the axis's q-slot (thread-private, read first).
// ---------------------------------------------------------------------------
template<int T>
__device__ __forceinline__ void attn1(
    u16* __restrict__ Qb, int n, int base, int stp, int hd)
{
  u16* qp = Qb + (size_t)n * QLD + hd * 16;
  u16x8 q0 = *(const u16x8*)(qp), q1 = *(const u16x8*)(qp + 8);
  float q[16];
  #pragma unroll
  for (int d = 0; d < 8; ++d) { q[d] = bf2f(q0[d]); q[d + 8] = bf2f(q1[d]); }

  float s[T];
  float m = -1e30f;
  #pragma unroll
  for (int j = 0; j < T; ++j) {
    const u16* kp = Qb + (size_t)(base + j * stp) * QLD + 256 + hd * 16;
    u16x8 k0 = *(const u16x8*)(kp), k1 = *(const u16x8*)(kp + 8);
    float a = 0.f;
    #pragma unroll
    for (int d = 0; d < 8; ++d) a += q[d] * bf2f(k0[d]) + q[d + 8] * bf2f(k1[d]);
    s[j] = a;
    m = fmaxf(m, a);
  }
  float sum = 0.f;
  float o[16];
  #pragma unroll
  for (int d = 0; d < 16; ++d) o[d] = 0.f;
  #pragma unroll
  for (int j = 0; j < T; ++j) {
    float pj = __expf(s[j] - m);
    sum += pj;
    const u16* vp = Qb + (size_t)(base + j * stp) * QLD + 512 + hd * 16;
    u16x8 w0 = *(const u16x8*)(vp), w1 = *(const u16x8*)(vp + 8);
    #pragma unroll
    for (int d = 0; d < 8; ++d) { o[d] += pj * bf2f(w0[d]); o[d + 8] += pj * bf2f(w1[d]); }
  }
  float inv = 1.0f / sum;
  u16x8 r0, r1;
  #pragma unroll
  for (int d = 0; d < 8; ++d) { r0[d] = f2bf(o[d] * inv); r1[d] = f2bf(o[d + 8] * inv); }
  *(u16x8*)(qp)     = r0;
  *(u16x8*)(qp + 8) = r1;
}

__global__ __launch_bounds__(256) void attn_hw(u16* __restrict__ QKV)
{
  const int tg = blockIdx.x * 256 + threadIdx.x;   // n*16 + hd
  const int hd = tg & 15, n = tg >> 4;
  int h  = (n % 20) / 5;
  int w5 = n % 5;
  attn1<4>(QKV + 768,  n, n - h * 5, 5, hd);
  attn1<5>(QKV + 1536, n, n - w5,    1, hd);
}

// ---------------------------------------------------------------------------
// final sigmoid over accumulated logits
// ---------------------------------------------------------------------------
__global__ __launch_bounds__(256) void sigmoid_kernel(
    const float* __restrict__ logit, const float* __restrict__ dec_b,
    float* __restrict__ out)
{
  int i = blockIdx.x * 256 + threadIdx.x;
  out[i] = 1.0f / (1.0f + __expf(-(logit[i] + dec_b[0])));
}

// ---------------------------------------------------------------------------
extern "C" void kernel_launch(void* const* d_in, const int* in_sizes, int n_in,
                              void* d_out, int out_size, void* d_ws, size_t ws_size,
                              hipStream_t stream) {
  const float* x     = (const float*)d_in[0];
  const float* pos_s = (const float*)d_in[1];
  const float* pos_h = (const float*)d_in[2];
  const float* pos_w = (const float*)d_in[3];
  const float* wq    = (const float*)d_in[4];   // (2,3,256,256)
  const float* wkv   = (const float*)d_in[5];   // (2,3,512,256)
  const float* wo_w  = (const float*)d_in[6];   // (2,3,256,256)
  const float* wo_b  = (const float*)d_in[7];   // (2,3,256)
  const float* dec_w = (const float*)d_in[8];   // (1,256)
  const float* dec_b = (const float*)d_in[9];   // (1,)
  float* out = (float*)d_out;

  char* ws = (char*)d_ws;
  u16*   xb    = (u16*)ws;                       // 20,971,520
  u16*   QKV   = (u16*)(ws + 20971520);          // 40960*2304*2 = 188,743,680
  u16*   wqp   = (u16*)(ws + 209715200);         // 2,359,296
  u16*   wop   = (u16*)(ws + 212074496);         // 786,432
  float* bsum  = (float*)(ws + 212860928);       // 2,048
  float* logit = (float*)(ws + 212862976);       // 163,840  (end ~213 MB)

  prep_kernel<<<2048, 256, 0, stream>>>(x, pos_s, pos_h, pos_w, xb);
  pack_all<<<(PK_T1 + PK_T2 + 512 + 255) / 256, 256, 0, stream>>>(
      wq, wkv, wo_w, wo_b, wqp, wop, bsum);
  hipMemsetAsync(logit, 0, NPOS * sizeof(float), stream);

  for (int l = 0; l < 2; ++l) {
    // all 3 axes' QKV in one N=2304 stream GEMM (weight rows adjacent)
    gemm_stream<8, 18, 4><<<1440, 256, 0, stream>>>(
        xb, wqp + (size_t)(l * 3) * 196608, QKV, QLD);
    attn_seq_mfma<<<2560, 256, 0, stream>>>(QKV);   // in-place O over seq-q
    attn_hw<<<2560, 256, 0, stream>>>(QKV);         // in-place O over H/W-q
    // merged out-projection (K=768 gathered from the three O-slots)
    if (l == 0)
      gemm_bt<3, 24, 2><<<640, 256, 0, stream>>>(
          QKV, wop, xb, bsum, nullptr, nullptr, 256);
    else
      gemm_bt<4, 24, 2><<<640, 256, 0, stream>>>(
          QKV, wop + 196608, nullptr, bsum + 256, dec_w, logit, 0);
  }

  sigmoid_kernel<<<NPOS / 256, 256, 0, stream>>>(logit, dec_b, out);
}

// Round 14
// 313.068 us; speedup vs baseline: 2.0408x; 1.0356x over previous
//
#include <hip/hip_runtime.h>
#include <stdint.h>

typedef unsigned short u16;
typedef u16 u16x8 __attribute__((ext_vector_type(8)));
typedef __bf16 bf16x8 __attribute__((ext_vector_type(8)));
typedef float f32x4 __attribute__((ext_vector_type(4)));
typedef float f32x16 __attribute__((ext_vector_type(16)));

#define NE   256
#define NPOS 40960     // 32*64*4*5
#define QLD  2304      // QKV row stride: [seq q|k|v][H q|k|v][W q|k|v]

__device__ __forceinline__ float bf2f(u16 h) {
  union { unsigned u; float f; } c; c.u = ((unsigned)h) << 16; return c.f;
}
__device__ __forceinline__ u16 f2bf(float f) {
  union { float f; unsigned u; } c; c.f = f;
  unsigned u = c.u;
  return (u16)((u + 0x7FFFu + ((u >> 16) & 1u)) >> 16);
}
__device__ __forceinline__ unsigned pkbf(float a, float b) {
  unsigned r;
  asm("v_cvt_pk_bf16_f32 %0, %1, %2" : "=v"(r) : "v"(a), "v"(b));
  return r;
}
__device__ __forceinline__ void gll16(const void* g, void* l) {
  __builtin_amdgcn_global_load_lds(
      (const __attribute__((address_space(1))) void*)g,
      (__attribute__((address_space(3))) void*)l, 16, 0, 0);
}
template<int N> __device__ __forceinline__ void waitvm() {
  if constexpr (N == 0)       asm volatile("s_waitcnt vmcnt(0)"  ::: "memory");
  else if constexpr (N == 2)  asm volatile("s_waitcnt vmcnt(2)"  ::: "memory");
  else if constexpr (N == 4)  asm volatile("s_waitcnt vmcnt(4)"  ::: "memory");
  else if constexpr (N == 8)  asm volatile("s_waitcnt vmcnt(8)"  ::: "memory");
}

// ---------------------------------------------------------------------------
// merged prep + weight packing (independent work, one dispatch):
//  blocks [0,2048): xb[n][e] = bf16(x + pos)
//  blocks [2048,..): wqp / wop / bsum packing
// ---------------------------------------------------------------------------
#define PK_T1 (6*768*256)
#define PK_T2 (2*256*768)
#define PREP_BLK 2048
#define PACK_BLK ((PK_T1 + PK_T2 + 512) / 256)
__global__ __launch_bounds__(256) void prep_pack(
    const float* __restrict__ x, const float* __restrict__ pos_s,
    const float* __restrict__ pos_h, const float* __restrict__ pos_w,
    u16* __restrict__ xb,
    const float* __restrict__ wq, const float* __restrict__ wkv,
    const float* __restrict__ wo, const float* __restrict__ wo_b,
    u16* __restrict__ wqp, u16* __restrict__ wop, float* __restrict__ bsum)
{
  __shared__ float Ls[256 * 21];
  const int tid = threadIdx.x;
  if (blockIdx.x < PREP_BLK) {
    const int bs = blockIdx.x;           // b*64+s
    const int s  = bs & 63;
    const float* xp = x + (size_t)bs * 5120;
    for (int i = tid; i < 5120; i += 256) {
      int e = i / 20, hw = i % 20;
      int h = hw / 5, w = hw % 5;
      float v = xp[i] + pos_s[s * 256 + e] + pos_h[e * 4 + h] + pos_w[e * 5 + w];
      Ls[e * 21 + hw] = v;
    }
    __syncthreads();
    u16* op = xb + (size_t)bs * 20 * 256;
    for (int i = tid; i < 5120; i += 256) {
      int nl = i >> 8, e = i & 255;
      op[nl * 256 + e] = f2bf(Ls[e * 21 + nl]);
    }
  } else {
    int i = (blockIdx.x - PREP_BLK) * 256 + tid;
    if (i < PK_T1) {
      int la = i / (768 * 256);
      int rem = i - la * (768 * 256);
      int r = rem >> 8, c = rem & 255;
      float v = (r < 256) ? wq[(size_t)la * 65536 + r * 256 + c] * 0.25f
                          : wkv[(size_t)la * 131072 + (r - 256) * 256 + c];
      wqp[i] = f2bf(v);
    } else if (i < PK_T1 + PK_T2) {
      int j = i - PK_T1;
      int l = j / 196608;
      int rem = j - l * 196608;
      int out = rem / 768, k = rem % 768;
      int a = k >> 8, in = k & 255;
      wop[j] = f2bf(wo[(size_t)(((l * 3 + a) * 256) + out) * 256 + in]);
    } else if (i < PK_T1 + PK_T2 + 512) {
      int j = i - PK_T1 - PK_T2;
      int l = j >> 8, c = j & 255;
      bsum[j] = wo_b[(l * 3 + 0) * 256 + c] + wo_b[(l * 3 + 1) * 256 + c]
              + wo_b[(l * 3 + 2) * 256 + c];
    }
  }
}

// ---------------------------------------------------------------------------
// STREAM GEMM: C[M][N] = A[M][K]*B[N][K]^T, bf16 out at ldc.
// B panel staged ONCE (kt-major); A double-buffered; continuous pipeline;
// seg-XOR bank swizzle (conflicts measured 0); setprio around MFMA (T5).
// ---------------------------------------------------------------------------
template<int NKT, int NBN, int TPB>
__global__ __launch_bounds__(256, 2) void gemm_stream(
    const u16* __restrict__ A, const u16* __restrict__ B,
    u16* __restrict__ Cb, int ldc)
{
  constexpr int K     = NKT * 32;
  constexpr int NSTEP = NKT * TPB;
  __shared__ alignas(16) u16 Bs[128 * K];        // 64 KB @ K=256
  __shared__ alignas(16) u16 As[2][128 * 32];    // 16 KB

  const int nblk = gridDim.x;
  const int bid  = blockIdx.x;
  const int mapped = (bid & 7) * (nblk >> 3) + (bid >> 3);   // XCD-chunked
  const int strip = mapped / NBN, bn = mapped % NBN;
  const int bm0 = strip * TPB;

  const int tid  = threadIdx.x;
  const int lane = tid & 63, w = tid >> 6;
  const int wr   = (w >> 1) * 64, wc = (w & 1) * 64;
  const int r16  = lane & 15, khi = lane >> 4;
  const int pofs = (khi ^ ((r16 >> 1) & 3)) * 8;   // swizzled seg offset (u16)

  const u16* gB = B + (size_t)bn * 128 * K;
  const u16* gA = A + (size_t)bm0 * 128 * K;

  #pragma unroll
  for (int b = 0; b < K / 16; ++b) {
    int slot = tid + b * 256;                    // 0 .. 128*K/8-1
    int kt = slot >> 9, rem = slot & 511;
    int row = rem >> 2, c = rem & 3;
    int cs = c ^ ((row >> 1) & 3);
    gll16(gB + (size_t)row * K + kt * 32 + cs * 8, (char*)Bs + slot * 16);
  }

  auto STAGE_A = [&](int g) {
    const int t = g / NKT, kt = g % NKT;
    const u16* tA = gA + (size_t)t * 128 * K + kt * 32;
    u16* dst = As[g & 1];
    #pragma unroll
    for (int r = 0; r < 2; ++r) {
      int i = tid + r * 256;
      int row = i >> 2, s = i & 3;
      int ss = s ^ ((row >> 1) & 3);
      gll16(tA + (size_t)row * K + ss * 8, (char*)dst + i * 16);
    }
  };

  f32x4 acc[4][4] = {};
  STAGE_A(0);

  for (int t = 0; t < TPB; ++t) {
    #pragma unroll
    for (int kt = 0; kt < NKT; ++kt) {
      const int g = t * NKT + kt;
      __builtin_amdgcn_s_barrier();
      if (g + 1 < NSTEP) { STAGE_A(g + 1); waitvm<2>(); }
      else               { waitvm<0>(); }
      asm volatile("" ::: "memory");

      const u16* Ab = As[g & 1];
      const u16* Bk = Bs + kt * (128 * 32);
      bf16x8 af[4], bfr[4];
      #pragma unroll
      for (int m = 0; m < 4; ++m)
        af[m] = *(const bf16x8*)(Ab + (wr + m * 16 + r16) * 32 + pofs);
      #pragma unroll
      for (int n = 0; n < 4; ++n)
        bfr[n] = *(const bf16x8*)(Bk + (wc + n * 16 + r16) * 32 + pofs);
      __builtin_amdgcn_s_setprio(1);
      #pragma unroll
      for (int m = 0; m < 4; ++m)
        #pragma unroll
        for (int n = 0; n < 4; ++n)
          acc[m][n] = __builtin_amdgcn_mfma_f32_16x16x32_bf16(af[m], bfr[n], acc[m][n], 0, 0, 0);
      __builtin_amdgcn_s_setprio(0);
      asm volatile("" ::: "memory");
    }
    const int row0 = (bm0 + t) * 128 + wr + khi * 4;
    const int col0 = bn * 128 + wc + r16;
    #pragma unroll
    for (int m = 0; m < 4; ++m)
      #pragma unroll
      for (int n = 0; n < 4; ++n)
        #pragma unroll
        for (int j = 0; j < 4; ++j) {
          Cb[(size_t)(row0 + m * 16 + j) * ldc + col0 + n * 16] = f2bf(acc[m][n][j]);
          acc[m][n][j] = 0.f;
        }
  }
}

// ---------------------------------------------------------------------------
// out-projection GEMM (K=768): A rows gathered from QKV's three O-slots
// (logical col k -> phys (k>>8)*768 + (k&255), row stride QLD). Swizzled LDS.
// MODE 3: Cb = bf16(acc+bias); 4: fused decode partial into logit
// ---------------------------------------------------------------------------
template<int MODE, int NKT, int NBN>
__global__ __launch_bounds__(256, 2) void gemm_bt(
    const u16* __restrict__ A, const u16* __restrict__ B,
    u16* __restrict__ Cb, const float* __restrict__ bias,
    const float* __restrict__ dw, float* __restrict__ logit,
    int ldc)
{
  constexpr int K   = NKT * 32;
  constexpr int TSZ = 256 * 32;
  __shared__ alignas(16) u16 smem[3 * TSZ];

  const int bid = blockIdx.x;
  const int cpx = gridDim.x >> 3;
  const int mapped = (bid & 7) * cpx + (bid >> 3);
  const int bm = mapped / NBN, bn = mapped % NBN;

  const int tid  = threadIdx.x;
  const int lane = tid & 63, w = tid >> 6;
  const int wr   = (w >> 1) * 64, wc = (w & 1) * 64;
  const int r16  = lane & 15, khi = lane >> 4;
  const int pofs = (khi ^ ((r16 >> 1) & 3)) * 8;

  f32x4 acc[4][4] = {};

  const u16* gA = A + (size_t)bm * 128 * QLD;
  const u16* gB = B + (size_t)bn * 128 * K;

  auto STAGE = [&](int kt, int which) {
    u16* As = smem + which * TSZ;
    u16* Bsl = As + 128 * 32;
    #pragma unroll
    for (int r = 0; r < 2; ++r) {
      int i = tid + r * 256;
      int row = i >> 2, s = i & 3;
      int col = kt * 32 + (s ^ ((row >> 1) & 3)) * 8;      // logical 0..767
      int phys = (col >> 8) * 768 + (col & 255);
      gll16(gA + (size_t)row * QLD + phys, (char*)As + i * 16);
    }
    #pragma unroll
    for (int r = 0; r < 2; ++r) {
      int i = tid + r * 256;
      int row = i >> 2, s = i & 3;
      int ss = s ^ ((row >> 1) & 3);
      gll16(gB + (size_t)row * K + kt * 32 + ss * 8, (char*)Bsl + i * 16);
    }
  };

  STAGE(0, 0);
  STAGE(1, 1);
  #pragma unroll
  for (int kt = 0; kt < NKT; ++kt) {
    const int cur = kt % 3;
    if (kt + 2 < NKT)      { STAGE(kt + 2, (kt + 2) % 3); waitvm<8>(); }
    else if (kt + 1 < NKT) { waitvm<4>(); }
    else                   { waitvm<0>(); }
    __builtin_amdgcn_s_barrier();
    asm volatile("" ::: "memory");

    const u16* As = smem + cur * TSZ;
    const u16* Bsl = As + 128 * 32;
    bf16x8 af[4], bfr[4];
    #pragma unroll
    for (int m = 0; m < 4; ++m)
      af[m] = *(const bf16x8*)(As + (wr + m * 16 + r16) * 32 + pofs);
    #pragma unroll
    for (int n = 0; n < 4; ++n)
      bfr[n] = *(const bf16x8*)(Bsl + (wc + n * 16 + r16) * 32 + pofs);
    __builtin_amdgcn_s_setprio(1);
    #pragma unroll
    for (int m = 0; m < 4; ++m)
      #pragma unroll
      for (int n = 0; n < 4; ++n)
        acc[m][n] = __builtin_amdgcn_mfma_f32_16x16x32_bf16(af[m], bfr[n], acc[m][n], 0, 0, 0);
    __builtin_amdgcn_s_setprio(0);

    asm volatile("" ::: "memory");
    __builtin_amdgcn_s_barrier();
  }

  const int row0 = bm * 128 + wr + khi * 4;
  const int col0 = bn * 128 + wc + r16;

  if constexpr (MODE == 4) {
    float dwv[4], bvv[4];
    #pragma unroll
    for (int n = 0; n < 4; ++n) {
      int c = col0 + n * 16;
      dwv[n] = dw[c];
      bvv[n] = bias[c];
    }
    #pragma unroll
    for (int m = 0; m < 4; ++m) {
      #pragma unroll
      for (int j = 0; j < 4; ++j) {
        float p = 0.f;
        #pragma unroll
        for (int n = 0; n < 4; ++n) p += (acc[m][n][j] + bvv[n]) * dwv[n];
        p += __shfl_xor(p, 1);
        p += __shfl_xor(p, 2);
        p += __shfl_xor(p, 4);
        p += __shfl_xor(p, 8);
        if (r16 == 0) atomicAdd(&logit[row0 + m * 16 + j], p);
      }
    }
  } else {
    #pragma unroll
    for (int m = 0; m < 4; ++m) {
      #pragma unroll
      for (int n = 0; n < 4; ++n) {
        int c = col0 + n * 16;
        float bv = bias[c];
        #pragma unroll
        for (int j = 0; j < 4; ++j) {
          int r = row0 + m * 16 + j;
          Cb[(size_t)r * ldc + c] = f2bf(acc[m][n][j] + bv);
        }
      }
    }
  }
}

// ---------------------------------------------------------------------------
// merged attention: blocks [0,2560) = seq (MFMA, wave per (group,head));
// blocks [2560,5120) = H+W (thread per (n,head)). All in-place over q-slots.
// ---------------------------------------------------------------------------
template<int T>
__device__ __forceinline__ void attn1(
    u16* __restrict__ Qb, int n, int base, int stp, int hd)
{
  u16* qp = Qb + (size_t)n * QLD + hd * 16;
  u16x8 q0 = *(const u16x8*)(qp), q1 = *(const u16x8*)(qp + 8);
  float q[16];
  #pragma unroll
  for (int d = 0; d < 8; ++d) { q[d] = bf2f(q0[d]); q[d + 8] = bf2f(q1[d]); }

  float s[T];
  float m = -1e30f;
  #pragma unroll
  for (int j = 0; j < T; ++j) {
    const u16* kp = Qb + (size_t)(base + j * stp) * QLD + 256 + hd * 16;
    u16x8 k0 = *(const u16x8*)(kp), k1 = *(const u16x8*)(kp + 8);
    float a = 0.f;
    #pragma unroll
    for (int d = 0; d < 8; ++d) a += q[d] * bf2f(k0[d]) + q[d + 8] * bf2f(k1[d]);
    s[j] = a;
    m = fmaxf(m, a);
  }
  float sum = 0.f;
  float o[16];
  #pragma unroll
  for (int d = 0; d < 16; ++d) o[d] = 0.f;
  #pragma unroll
  for (int j = 0; j < T; ++j) {
    float pj = __expf(s[j] - m);
    sum += pj;
    const u16* vp = Qb + (size_t)(base + j * stp) * QLD + 512 + hd * 16;
    u16x8 w0 = *(const u16x8*)(vp), w1 = *(const u16x8*)(vp + 8);
    #pragma unroll
    for (int d = 0; d < 8; ++d) { o[d] += pj * bf2f(w0[d]); o[d + 8] += pj * bf2f(w1[d]); }
  }
  float inv = 1.0f / sum;
  u16x8 r0, r1;
  #pragma unroll
  for (int d = 0; d < 8; ++d) { r0[d] = f2bf(o[d] * inv); r1[d] = f2bf(o[d + 8] * inv); }
  *(u16x8*)(qp)     = r0;
  *(u16x8*)(qp + 8) = r1;
}

__global__ __launch_bounds__(256) void attn_all(u16* __restrict__ QKV)
{
  if (blockIdx.x < 2560) {
    // ---- seq axis via MFMA ----
    const int w = threadIdx.x >> 6, lane = threadIdx.x & 63;
    const int wid = blockIdx.x * 4 + w;
    const int hd = wid & 15, g = wid >> 4;
    const int gb = g / 20, gr = g % 20;
    const int nbase = gb * 1280 + gr;
    const int lo = lane & 31, hi = lane >> 5;

    bf16x8 kf[2], qf[2];
    #pragma unroll
    for (int t = 0; t < 2; ++t) {
      size_t r = (size_t)(nbase + (lo + 32 * t) * 20) * QLD;
      kf[t] = *(const bf16x8*)(QKV + r + 256 + hd * 16 + hi * 8);
      qf[t] = *(const bf16x8*)(QKV + r +       hd * 16 + hi * 8);
    }
    union { u16 a[8]; bf16x8 v; } vt[4];
    #pragma unroll
    for (int c = 0; c < 4; ++c)
      #pragma unroll
      for (int j = 0; j < 8; ++j)
        vt[c].a[j] = QKV[(size_t)(nbase + (c * 16 + hi * 8 + j) * 20) * QLD
                         + 512 + hd * 16 + lo];

    f32x16 s00 = {}, s10 = {}, s01 = {}, s11 = {};
    s00 = __builtin_amdgcn_mfma_f32_32x32x16_bf16(kf[0], qf[0], s00, 0, 0, 0);
    s10 = __builtin_amdgcn_mfma_f32_32x32x16_bf16(kf[1], qf[0], s10, 0, 0, 0);
    s01 = __builtin_amdgcn_mfma_f32_32x32x16_bf16(kf[0], qf[1], s01, 0, 0, 0);
    s11 = __builtin_amdgcn_mfma_f32_32x32x16_bf16(kf[1], qf[1], s11, 0, 0, 0);

    auto run_qt = [&](f32x16 t0, f32x16 t1, int qt) {
      float m = -1e30f;
      #pragma unroll
      for (int r = 0; r < 16; ++r) { m = fmaxf(m, t0[r]); m = fmaxf(m, t1[r]); }
      m = fmaxf(m, __shfl_xor(m, 32));
      const float C = 1.4426950408889634f;
      float mc = m * C;
      float sum = 0.f;
      #pragma unroll
      for (int r = 0; r < 16; ++r) {
        float p0 = __builtin_amdgcn_exp2f(t0[r] * C - mc);
        float p1 = __builtin_amdgcn_exp2f(t1[r] * C - mc);
        t0[r] = p0; t1[r] = p1; sum += p0; sum += p1;
      }
      sum += __shfl_xor(sum, 32);
      float inv = __builtin_amdgcn_rcpf(sum);
      #pragma unroll
      for (int r = 0; r < 16; ++r) { t0[r] *= inv; t1[r] *= inv; }

      f32x16 oa = {};
      #pragma unroll
      for (int c = 0; c < 4; ++c) {
        const int rb = 8 * (c & 1);
        const f32x16& tt = (c < 2) ? t0 : t1;
        unsigned X0 = pkbf(tt[rb + 0], tt[rb + 1]);
        unsigned X1 = pkbf(tt[rb + 2], tt[rb + 3]);
        unsigned Y0 = pkbf(tt[rb + 4], tt[rb + 5]);
        unsigned Y1 = pkbf(tt[rb + 6], tt[rb + 7]);
        unsigned X0p = __shfl_xor((int)X0, 32), X1p = __shfl_xor((int)X1, 32);
        unsigned Y0p = __shfl_xor((int)Y0, 32), Y1p = __shfl_xor((int)Y1, 32);
        union { unsigned u[4]; bf16x8 v; } pf;
        pf.u[0] = hi ? Y0p : X0;
        pf.u[1] = hi ? Y1p : X1;
        pf.u[2] = hi ? Y0  : X0p;
        pf.u[3] = hi ? Y1  : X1p;
        oa = __builtin_amdgcn_mfma_f32_32x32x16_bf16(vt[c].v, pf.v, oa, 0, 0, 0);
      }
      unsigned P0 = pkbf(oa[0], oa[1]);
      unsigned P1 = pkbf(oa[2], oa[3]);
      unsigned P2 = pkbf(oa[4], oa[5]);
      unsigned P3 = pkbf(oa[6], oa[7]);
      unsigned sP0 = __shfl_xor((int)P0, 32), sP1 = __shfl_xor((int)P1, 32);
      unsigned sP2 = __shfl_xor((int)P2, 32), sP3 = __shfl_xor((int)P3, 32);
      union { unsigned u[4]; u16x8 v; } ov;
      ov.u[0] = hi ? sP2 : P0;
      ov.u[1] = hi ? sP3 : P1;
      ov.u[2] = hi ? P2  : sP0;
      ov.u[3] = hi ? P3  : sP1;
      u16* po = QKV + (size_t)(nbase + (qt * 32 + lo) * 20) * QLD + hd * 16 + hi * 8;
      *(u16x8*)po = ov.v;
    };
    run_qt(s00, s10, 0);
    run_qt(s01, s11, 1);
  } else {
    // ---- H and W axes ----
    const int tg = (blockIdx.x - 2560) * 256 + threadIdx.x;   // n*16 + hd
    const int hd = tg & 15, n = tg >> 4;
    int h  = (n % 20) / 5;
    int w5 = n % 5;
    attn1<4>(QKV + 768,  n, n - h * 5, 5, hd);
    attn1<5>(QKV + 1536, n, n - w5,    1, hd);
  }
}

// ---------------------------------------------------------------------------
// final sigmoid over accumulated logits
// ---------------------------------------------------------------------------
__global__ __launch_bounds__(256) void sigmoid_kernel(
    const float* __restrict__ logit, const float* __restrict__ dec_b,
    float* __restrict__ out)
{
  int i = blockIdx.x * 256 + threadIdx.x;
  out[i] = 1.0f / (1.0f + __expf(-(logit[i] + dec_b[0])));
}

// ---------------------------------------------------------------------------
extern "C" void kernel_launch(void* const* d_in, const int* in_sizes, int n_in,
                              void* d_out, int out_size, void* d_ws, size_t ws_size,
                              hipStream_t stream) {
  const float* x     = (const float*)d_in[0];
  const float* pos_s = (const float*)d_in[1];
  const float* pos_h = (const float*)d_in[2];
  const float* pos_w = (const float*)d_in[3];
  const float* wq    = (const float*)d_in[4];   // (2,3,256,256)
  const float* wkv   = (const float*)d_in[5];   // (2,3,512,256)
  const float* wo_w  = (const float*)d_in[6];   // (2,3,256,256)
  const float* wo_b  = (const float*)d_in[7];   // (2,3,256)
  const float* dec_w = (const float*)d_in[8];   // (1,256)
  const float* dec_b = (const float*)d_in[9];   // (1,)
  float* out = (float*)d_out;

  char* ws = (char*)d_ws;
  u16*   xb    = (u16*)ws;                       // 20,971,520
  u16*   QKV   = (u16*)(ws + 20971520);          // 40960*2304*2 = 188,743,680
  u16*   wqp   = (u16*)(ws + 209715200);         // 2,359,296
  u16*   wop   = (u16*)(ws + 212074496);         // 786,432
  float* bsum  = (float*)(ws + 212860928);       // 2,048
  float* logit = (float*)(ws + 212862976);       // 163,840  (end ~213 MB)

  prep_pack<<<PREP_BLK + PACK_BLK, 256, 0, stream>>>(
      x, pos_s, pos_h, pos_w, xb, wq, wkv, wo_w, wo_b, wqp, wop, bsum);
  hipMemsetAsync(logit, 0, NPOS * sizeof(float), stream);

  for (int l = 0; l < 2; ++l) {
    // all 3 axes' QKV in one N=2304 stream GEMM (weight rows adjacent)
    gemm_stream<8, 18, 4><<<1440, 256, 0, stream>>>(
        xb, wqp + (size_t)(l * 3) * 196608, QKV, QLD);
    attn_all<<<5120, 256, 0, stream>>>(QKV);        // seq + H + W, in-place
    // merged out-projection (K=768 gathered from the three O-slots)
    if (l == 0)
      gemm_bt<3, 24, 2><<<640, 256, 0, stream>>>(
          QKV, wop, xb, bsum, nullptr, nullptr, 256);
    else
      gemm_bt<4, 24, 2><<<640, 256, 0, stream>>>(
          QKV, wop + 196608, nullptr, bsum + 256, dec_w, logit, 0);
  }

  sigmoid_kernel<<<NPOS / 256, 256, 0, stream>>>(logit, dec_b, out);
}